// Round 3
// baseline (995.002 us; speedup 1.0000x reference)
//
#include <hip/hip_runtime.h>

typedef unsigned long long u64;
typedef float  floatx4 __attribute__((ext_vector_type(4)));
typedef short  short8  __attribute__((ext_vector_type(8)));

#define T_ 4
#define B_ 16
#define C_ 512
#define N_ 256
#define M_ 16384   // T*B*N

static __device__ __forceinline__ float b2f(unsigned short u){
  union { unsigned int i; float f; } x; x.i = ((unsigned int)u) << 16; return x.f;
}
static __device__ __forceinline__ unsigned short f2b(float f){
  unsigned int u = __float_as_uint(f);
  unsigned int r = (u + 0x7FFFu + ((u >> 16) & 1u)) >> 16;
  return (unsigned short)r;
}
static __device__ __forceinline__ float sigmoidf_(float x){ return 1.f / (1.f + expf(-x)); }

// ------- split all weights into bf16 hi + bf16 lo (concatenated qkv|proj|fc1|fc2) -------
__global__ __launch_bounds__(256) void wsplit_kernel(const float* __restrict__ qkvw,
    const float* __restrict__ projw, const float* __restrict__ fc1w,
    const float* __restrict__ fc2w, unsigned short* __restrict__ hi,
    unsigned short* __restrict__ lo){
  int i = blockIdx.x * 256 + threadIdx.x;        // 0 .. 3,145,727
  const float* src; int off;
  if (i < 786432)      { src = qkvw; off = i; }
  else if (i < 1048576){ src = projw; off = i - 786432; }
  else if (i < 2097152){ src = fc1w;  off = i - 1048576; }
  else                 { src = fc2w;  off = i - 2097152; }
  float f = src[off];
  unsigned short h = f2b(f);
  float r = f - b2f(h);
  hi[i] = h; lo[i] = f2b(r);
}

// ---------------- LIF over x: s = lif(x, lif_w[0]), x-layout [T,B,C,N] ----------------
__global__ __launch_bounds__(256) void lif_x_kernel(const float* __restrict__ x,
    unsigned short* __restrict__ s, const float* __restrict__ lifw){
  int e = blockIdx.x * 256 + threadIdx.x;        // 0 .. B*C*N-1
  const int E = B_ * C_ * N_;                    // 2,097,152
  float D = sigmoidf_(lifw[0]);
  float v = 0.f;
  #pragma unroll
  for (int t = 0; t < T_; ++t){
    float xv = x[(size_t)t * E + e];
    v = v + (xv - v) * D;
    bool sp = v >= 1.0f;
    s[(size_t)t * E + e] = sp ? (unsigned short)0x3F80u : (unsigned short)0u;
    v = sp ? 0.f : v;
  }
}

// ---- depthwise 3x3 conv on spikes + residual + transpose to [T,B,N,C] f32 ----
__global__ __launch_bounds__(256) void conv_pos_kernel(const float* __restrict__ x,
    const unsigned short* __restrict__ s, const float* __restrict__ cw,
    const float* __restrict__ cb, float* __restrict__ xt){
  int tid = blockIdx.x * 256 + threadIdx.x;      // (tb*256+n)*512 + c
  int c  = tid & 511;
  int n  = (tid >> 9) & 255;
  int tb = tid >> 17;
  int hh = n >> 4, wwp = n & 15;
  const unsigned short* sb = s + ((size_t)(tb * C_ + c)) * N_;
  float acc = cb[c];
  #pragma unroll
  for (int dy = -1; dy <= 1; ++dy){
    int y = hh + dy; if ((unsigned)y >= 16u) continue;
    #pragma unroll
    for (int dx = -1; dx <= 1; ++dx){
      int xw = wwp + dx; if ((unsigned)xw >= 16u) continue;
      if (sb[y * 16 + xw]) acc += cw[c * 9 + (dy + 1) * 3 + (dx + 1)];
    }
  }
  float xv = x[((size_t)(tb * C_ + c)) * N_ + n];
  xt[tid] = xv + acc;
}

// ---------------- fused LayerNorm (over C) + LIF (over T) -> bf16 spikes ----------------
__global__ __launch_bounds__(256) void ln_lif_kernel(const float* __restrict__ xt,
    const float* __restrict__ g, const float* __restrict__ be,
    const float* __restrict__ lifw, int lidx, unsigned short* __restrict__ spk){
  int bn = blockIdx.x; int tid = threadIdx.x;
  int c0 = tid * 2;
  __shared__ float red[256];
  float D = sigmoidf_(lifw[lidx]);
  float g0 = g[c0], g1 = g[c0 + 1];
  float b0 = be[c0], b1 = be[c0 + 1];
  float v0 = 0.f, v1 = 0.f;
  for (int t = 0; t < T_; ++t){
    size_t base = ((size_t)t * 4096 + bn) * 512;
    float x0 = xt[base + c0], x1 = xt[base + c0 + 1];
    red[tid] = x0 + x1; __syncthreads();
    for (int st = 128; st > 0; st >>= 1){ if (tid < st) red[tid] += red[tid + st]; __syncthreads(); }
    float mean = red[0] * (1.f / 512.f); __syncthreads();
    float d0 = x0 - mean, d1 = x1 - mean;
    red[tid] = d0 * d0 + d1 * d1; __syncthreads();
    for (int st = 128; st > 0; st >>= 1){ if (tid < st) red[tid] += red[tid + st]; __syncthreads(); }
    float var = red[0] * (1.f / 512.f); __syncthreads();
    float inv = 1.f / sqrtf(var + 1e-5f);
    float y0 = d0 * inv * g0 + b0;
    float y1 = d1 * inv * g1 + b1;
    v0 = v0 + (y0 - v0) * D; bool s0 = v0 >= 1.f;
    v1 = v1 + (y1 - v1) * D; bool s1 = v1 >= 1.f;
    spk[base + c0]     = s0 ? (unsigned short)0x3F80u : (unsigned short)0u;
    spk[base + c0 + 1] = s1 ? (unsigned short)0x3F80u : (unsigned short)0u;
    v0 = s0 ? 0.f : v0; v1 = s1 ? 0.f : v1;
  }
}

// ------- LIF over [16384,512] f32 pre-acts -> bit-packed spikes [16384,8] u64 -------
__global__ __launch_bounds__(256) void lif_pack_kernel(const float* __restrict__ in,
    u64* __restrict__ bits, const float* __restrict__ lifw, int lidx){
  int tid = blockIdx.x * 256 + threadIdx.x;      // 0 .. 4096*512-1
  int j = tid & 511; int bn = tid >> 9;
  int lane = threadIdx.x & 63; int wj = j >> 6;
  float D = sigmoidf_(lifw[lidx]);
  float v = 0.f;
  #pragma unroll
  for (int t = 0; t < T_; ++t){
    int m = t * 4096 + bn;
    float xv = in[(size_t)m * 512 + j];
    v = v + (xv - v) * D;
    bool sp = v >= 1.f;
    u64 bal = __ballot(sp);
    if (lane == 0) bits[(size_t)m * 8 + wj] = bal;
    v = sp ? 0.f : v;
  }
}

// ------- LIF over [16384,512] f32 pre-acts -> bf16 spikes [16384,512] -------
__global__ __launch_bounds__(256) void lif_spike_kernel(const float* __restrict__ in,
    unsigned short* __restrict__ out, const float* __restrict__ lifw, int lidx){
  int tid = blockIdx.x * 256 + threadIdx.x;
  int j = tid & 511; int bn = tid >> 9;
  float D = sigmoidf_(lifw[lidx]);
  float v = 0.f;
  #pragma unroll
  for (int t = 0; t < T_; ++t){
    int m = t * 4096 + bn;
    float xv = in[(size_t)m * 512 + j];
    v = v + (xv - v) * D;
    bool sp = v >= 1.f;
    out[(size_t)m * 512 + j] = sp ? (unsigned short)0x3F80u : (unsigned short)0u;
    v = sp ? 0.f : v;
  }
}

// ---- NT GEMM, split-bf16 weights: out[m,n] = sum_k A[m,k]*(Whi+Wlo)[n,k] (+bias)(+resid) ----
// A: [16384,lda] bf16 spikes; Whi/Wlo: bf16; out: f32 [16384,ldo]
__global__ __launch_bounds__(256) void gemm_nt_kernel(
    const unsigned short* __restrict__ A, int lda,
    const unsigned short* __restrict__ Whi, const unsigned short* __restrict__ Wlo, int ldw,
    const float* __restrict__ bias, const float* __restrict__ resid,
    float* __restrict__ out, int ldo, int K){
  __shared__ __align__(16) unsigned short As[128 * 40];
  __shared__ __align__(16) unsigned short Bh[128 * 40];
  __shared__ __align__(16) unsigned short Bl[128 * 40];
  int m0 = blockIdx.x * 128, n0 = blockIdx.y * 128;
  int tid = threadIdx.x; int lane = tid & 63, wid = tid >> 6;
  int wm = (wid >> 1) * 64, wn = (wid & 1) * 64;
  int lm = lane & 15, lk = (lane >> 4) * 8;
  int lr = tid >> 2; int lc = (tid & 3) * 8;
  const unsigned short* pa0 = A   + (size_t)(m0 + lr) * lda + lc;
  const unsigned short* pa1 = A   + (size_t)(m0 + 64 + lr) * lda + lc;
  const unsigned short* ph0 = Whi + (size_t)(n0 + lr) * ldw + lc;
  const unsigned short* ph1 = Whi + (size_t)(n0 + 64 + lr) * ldw + lc;
  const unsigned short* pl0 = Wlo + (size_t)(n0 + lr) * ldw + lc;
  const unsigned short* pl1 = Wlo + (size_t)(n0 + 64 + lr) * ldw + lc;
  floatx4 acc[4][4];
  #pragma unroll
  for (int i = 0; i < 4; ++i)
    #pragma unroll
    for (int j = 0; j < 4; ++j){ acc[i][j][0] = 0.f; acc[i][j][1] = 0.f; acc[i][j][2] = 0.f; acc[i][j][3] = 0.f; }

  for (int kb = 0; kb < K; kb += 32){
    *(uint4*)(&As[lr * 40 + lc])        = *(const uint4*)(pa0 + kb);
    *(uint4*)(&As[(64 + lr) * 40 + lc]) = *(const uint4*)(pa1 + kb);
    *(uint4*)(&Bh[lr * 40 + lc])        = *(const uint4*)(ph0 + kb);
    *(uint4*)(&Bh[(64 + lr) * 40 + lc]) = *(const uint4*)(ph1 + kb);
    *(uint4*)(&Bl[lr * 40 + lc])        = *(const uint4*)(pl0 + kb);
    *(uint4*)(&Bl[(64 + lr) * 40 + lc]) = *(const uint4*)(pl1 + kb);
    __syncthreads();
    short8 af[4], bh[4], bl[4];
    #pragma unroll
    for (int im = 0; im < 4; ++im) af[im] = *(const short8*)(&As[(wm + im * 16 + lm) * 40 + lk]);
    #pragma unroll
    for (int in = 0; in < 4; ++in){
      bh[in] = *(const short8*)(&Bh[(wn + in * 16 + lm) * 40 + lk]);
      bl[in] = *(const short8*)(&Bl[(wn + in * 16 + lm) * 40 + lk]);
    }
    #pragma unroll
    for (int im = 0; im < 4; ++im)
      #pragma unroll
      for (int in = 0; in < 4; ++in){
        acc[im][in] = __builtin_amdgcn_mfma_f32_16x16x32_bf16(af[im], bh[in], acc[im][in], 0, 0, 0);
        acc[im][in] = __builtin_amdgcn_mfma_f32_16x16x32_bf16(af[im], bl[in], acc[im][in], 0, 0, 0);
      }
    __syncthreads();
  }
  #pragma unroll
  for (int im = 0; im < 4; ++im){
    int row0 = m0 + wm + im * 16 + ((lane >> 4) << 2);
    #pragma unroll
    for (int in = 0; in < 4; ++in){
      int col = n0 + wn + in * 16 + lm;
      float bv = bias ? bias[col] : 0.f;
      #pragma unroll
      for (int r = 0; r < 4; ++r){
        size_t idx = (size_t)(row0 + r) * ldo + col;
        float v = acc[im][in][r] + bv;
        if (resid) v += resid[idx];
        out[idx] = v;
      }
    }
  }
}

// ---- spiking linear attention per (t,b,h) from bit-packed spikes: a = q @ (k^T v) * 0.125 ----
// bits layout: [part(q=0,k=1,v=2)][m=0..16383][h=0..7] u64 of 64 channel-bits
__global__ __launch_bounds__(256) void attn_kernel(const u64* __restrict__ bits,
    float* __restrict__ aout){
  int tbh = blockIdx.x;                          // 512
  int h = tbh & 7, b = (tbh >> 3) & 15, t = tbh >> 7;
  int m0 = t * 4096 + b * 256;
  int tid = threadIdx.x;
  __shared__ u64 QW[256], KW[256], VW[256];
  __shared__ u64 kbt[64][4], vbt[64][4];
  __shared__ float kvm[64][64];
  {
    size_t base = (size_t)(m0 + tid) * 8 + h;
    QW[tid] = bits[base];
    KW[tid] = bits[131072 + base];
    VW[tid] = bits[262144 + base];
  }
  __syncthreads();
  {
    int i = tid & 63, w = tid >> 6;
    const u64* kwp = &KW[w * 64];
    const u64* vwp = &VW[w * 64];
    u64 bk = 0, bv = 0;
    for (int nn = 0; nn < 64; ++nn){
      bk |= ((kwp[nn] >> i) & 1ull) << nn;
      bv |= ((vwp[nn] >> i) & 1ull) << nn;
    }
    kbt[i][w] = bk; vbt[i][w] = bv;
  }
  __syncthreads();
  #pragma unroll
  for (int e = 0; e < 16; ++e){
    int idx = tid * 16 + e;
    int i = idx >> 6, j = idx & 63;
    int cnt = __popcll(kbt[i][0] & vbt[j][0]) + __popcll(kbt[i][1] & vbt[j][1])
            + __popcll(kbt[i][2] & vbt[j][2]) + __popcll(kbt[i][3] & vbt[j][3]);
    kvm[i][j] = (float)cnt;
  }
  __syncthreads();
  {
    u64 bq = QW[tid];
    floatx4 acc[16];
    #pragma unroll
    for (int jj = 0; jj < 16; ++jj){ acc[jj][0] = 0.f; acc[jj][1] = 0.f; acc[jj][2] = 0.f; acc[jj][3] = 0.f; }
    for (int i = 0; i < 64; ++i){
      float qf = (float)((bq >> i) & 1ull);
      const floatx4* row = (const floatx4*)(&kvm[i][0]);
      #pragma unroll
      for (int jj = 0; jj < 16; ++jj) acc[jj] += row[jj] * qf;
    }
    float* orow = aout + (size_t)(m0 + tid) * 512 + h * 64;
    #pragma unroll
    for (int jj = 0; jj < 16; ++jj)
      *(floatx4*)(orow + jj * 4) = acc[jj] * 0.125f;
  }
}

// ---------------- final transpose [T,B,N,C] f32 -> [T,B,C,H,W] f32 ----------------
__global__ __launch_bounds__(256) void out_kernel(const float* __restrict__ xt,
    float* __restrict__ out){
  int o = blockIdx.x * 256 + threadIdx.x;
  int n = o & 255; int c = (o >> 8) & 511; int tb = o >> 17;
  out[o] = xt[((size_t)(tb * 256 + n)) * 512 + c];
}

extern "C" void kernel_launch(void* const* d_in, const int* in_sizes, int n_in,
                              void* d_out, int out_size, void* d_ws, size_t ws_size,
                              hipStream_t stream){
  const float* x     = (const float*)d_in[0];
  const float* convw = (const float*)d_in[1];
  const float* convb = (const float*)d_in[2];
  const float* ln1g  = (const float*)d_in[3];
  const float* ln1b  = (const float*)d_in[4];
  const float* qkvw  = (const float*)d_in[5];
  const float* projw = (const float*)d_in[6];
  const float* projb = (const float*)d_in[7];
  const float* ln2g  = (const float*)d_in[8];
  const float* ln2b  = (const float*)d_in[9];
  const float* fc1w  = (const float*)d_in[10];
  const float* fc1b  = (const float*)d_in[11];
  const float* fc2w  = (const float*)d_in[12];
  const float* fc2b  = (const float*)d_in[13];
  const float* lifw  = (const float*)d_in[14];
  float* outp = (float*)d_out;

  // workspace layout (total ~116.4 MB)
  char* wsb = (char*)d_ws;
  float* XT           = (float*)wsb;                            // [16384,512] f32   33.5 MB
  float* CH           = (float*)(wsb + 33554432);               // [16384,512] f32   33.5 MB
  unsigned short* SPK = (unsigned short*)(wsb + 67108864);      // [16384,512] bf16  16.8 MB
  unsigned short* HC  = (unsigned short*)(wsb + 83886080);      // [16384,512] bf16  16.8 MB
  unsigned short* WHI = (unsigned short*)(wsb + 100663296);     // 3,145,728 bf16     6.3 MB
  unsigned short* WLO = (unsigned short*)(wsb + 106954752);     // 3,145,728 bf16     6.3 MB
  u64* QBITS          = (u64*)(wsb + 113246208);                // [3,16384,8] u64    3.1 MB
  const int OFF_QKV = 0, OFF_PROJ = 786432, OFF_FC1 = 1048576, OFF_FC2 = 2097152;

  // 0. split weights into bf16 hi/lo
  wsplit_kernel<<<12288, 256, 0, stream>>>(qkvw, projw, fc1w, fc2w, WHI, WLO);
  // 1. s = lif(x)
  lif_x_kernel<<<8192, 256, 0, stream>>>(x, SPK, lifw);
  // 2. xt = x + dwconv3x3(s) + conv_b, transposed to [T,B,N,C]
  conv_pos_kernel<<<32768, 256, 0, stream>>>(x, SPK, convw, convb, XT);
  // 3. h1 = lif(LN1(xt)) -> SPK
  ln_lif_kernel<<<4096, 256, 0, stream>>>(XT, ln1g, ln1b, lifw, 1, SPK);
  // 4. qkv = h1 @ qkv_w^T -> LIF -> bit-packed q,k,v
  for (int p = 0; p < 3; ++p){
    gemm_nt_kernel<<<dim3(128, 4), 256, 0, stream>>>(SPK, 512,
        WHI + OFF_QKV + (size_t)p * 262144, WLO + OFF_QKV + (size_t)p * 262144, 512,
        nullptr, nullptr, CH, 512, 512);
    lif_pack_kernel<<<8192, 256, 0, stream>>>(CH, QBITS + (size_t)p * 131072, lifw, 2 + p);
  }
  // 5. linear attention -> CH (f32 pre-acts)
  attn_kernel<<<512, 256, 0, stream>>>(QBITS, CH);
  // 6. a_s = lif(a) -> SPK
  lif_spike_kernel<<<8192, 256, 0, stream>>>(CH, SPK, lifw, 5);
  // 7. xt += a_s @ proj_w^T + proj_b
  gemm_nt_kernel<<<dim3(128, 4), 256, 0, stream>>>(SPK, 512,
      WHI + OFF_PROJ, WLO + OFF_PROJ, 512, projb, XT, XT, 512, 512);
  // 8. h2 = lif(LN2(xt)) -> SPK
  ln_lif_kernel<<<4096, 256, 0, stream>>>(XT, ln2g, ln2b, lifw, 6, SPK);
  // 9. MLP, K-chunked over hidden: per chunk fc1 -> LIF -> fc2-accumulate into XT
  for (int hcb = 0; hcb < 4; ++hcb){
    gemm_nt_kernel<<<dim3(128, 4), 256, 0, stream>>>(SPK, 512,
        WHI + OFF_FC1 + (size_t)hcb * 262144, WLO + OFF_FC1 + (size_t)hcb * 262144, 512,
        fc1b + hcb * 512, nullptr, CH, 512, 512);
    lif_spike_kernel<<<8192, 256, 0, stream>>>(CH, HC, lifw, 7);
    gemm_nt_kernel<<<dim3(128, 4), 256, 0, stream>>>(HC, 512,
        WHI + OFF_FC2 + hcb * 512, WLO + OFF_FC2 + hcb * 512, 2048,
        (hcb == 0 ? fc2b : nullptr), XT, XT, 512, 512);
  }
  // 10. transpose back to [T,B,C,H,W] f32
  out_kernel<<<32768, 256, 0, stream>>>(XT, outp);
}

// Round 4
// 699.796 us; speedup vs baseline: 1.4218x; 1.4218x over previous
//
#include <hip/hip_runtime.h>

typedef unsigned long long u64;
typedef float  floatx4 __attribute__((ext_vector_type(4)));
typedef short  short8  __attribute__((ext_vector_type(8)));

#define T_ 4
#define B_ 16
#define C_ 512
#define N_ 256
#define M_ 16384   // T*B*N

static __device__ __forceinline__ float b2f(unsigned short u){
  union { unsigned int i; float f; } x; x.i = ((unsigned int)u) << 16; return x.f;
}
static __device__ __forceinline__ unsigned short f2b(float f){
  unsigned int u = __float_as_uint(f);
  unsigned int r = (u + 0x7FFFu + ((u >> 16) & 1u)) >> 16;
  return (unsigned short)r;
}
static __device__ __forceinline__ float sigmoidf_(float x){ return 1.f / (1.f + expf(-x)); }

// async global->LDS, 16 B per lane; lds base must be wave-uniform
static __device__ __forceinline__ void gll16(const void* g, void* l){
  __builtin_amdgcn_global_load_lds(
      (const __attribute__((address_space(1))) void*)g,
      (__attribute__((address_space(3))) void*)l, 16, 0, 0);
}

// ------- split all weights into bf16 hi + bf16 lo (concatenated qkv|proj|fc1|fc2) -------
__global__ __launch_bounds__(256) void wsplit_kernel(const float* __restrict__ qkvw,
    const float* __restrict__ projw, const float* __restrict__ fc1w,
    const float* __restrict__ fc2w, unsigned short* __restrict__ hi,
    unsigned short* __restrict__ lo){
  int i = blockIdx.x * 256 + threadIdx.x;        // 0 .. 3,145,727
  const float* src; int off;
  if (i < 786432)      { src = qkvw; off = i; }
  else if (i < 1048576){ src = projw; off = i - 786432; }
  else if (i < 2097152){ src = fc1w;  off = i - 1048576; }
  else                 { src = fc2w;  off = i - 2097152; }
  float f = src[off];
  unsigned short h = f2b(f);
  float r = f - b2f(h);
  hi[i] = h; lo[i] = f2b(r);
}

// ---- FUSED: lif(x) + depthwise 3x3 conv + residual + transpose to [T,B,N,C] f32 ----
// grid: 16 (b) x 32 (channel groups of 16); block 256
__global__ __launch_bounds__(256) void conv_lif_kernel(const float* __restrict__ x,
    const float* __restrict__ cw, const float* __restrict__ cb,
    const float* __restrict__ lifw, float* __restrict__ xt){
  __shared__ __align__(16) float xs[16 * 260];   // [ch][px], stride 260 (16B-aligned rows)
  __shared__ u64 sbits[16][5];                   // [ch][word], 64 pixel-bits per word
  int bb = blockIdx.x & 15, cg = blockIdx.x >> 4;
  int c0 = cg * 16;
  int tid = threadIdx.x;
  int lane = tid & 63, w = tid >> 6;
  int cl = tid & 15;
  float D = sigmoidf_(lifw[0]);
  // preload this thread's conv weights (channel c0+cl) and bias
  float cwv[9];
  #pragma unroll
  for (int j = 0; j < 9; ++j) cwv[j] = cw[(c0 + cl) * 9 + j];
  float cbv = cb[c0 + cl];
  float v[16];
  #pragma unroll
  for (int k = 0; k < 16; ++k) v[k] = 0.f;

  for (int t = 0; t < T_; ++t){
    // stage x[t][bb][c0+k][0..255] rows into LDS (wave w does rows w,w+4,w+8,w+12)
    #pragma unroll
    for (int j = 0; j < 4; ++j){
      int kk = __builtin_amdgcn_readfirstlane(w + 4 * j);
      const float* grow = x + (((size_t)t * 16 + bb) * 512 + c0 + kk) * 256 + lane * 4;
      gll16(grow, &xs[kk * 260]);
    }
    __syncthreads();
    // LIF: thread = pixel tid, loops channels; ballot -> spike bitmasks
    #pragma unroll
    for (int k = 0; k < 16; ++k){
      float xv = xs[k * 260 + tid];
      v[k] = v[k] + (xv - v[k]) * D;
      bool sp = v[k] >= 1.f;
      u64 bal = __ballot(sp);
      if (lane == 0) sbits[k][w] = bal;
      v[k] = sp ? 0.f : v[k];
    }
    __syncthreads();
    // conv + residual + transposed store: thread = (cl=tid&15, n = (tid>>4) + 16*i)
    u64 sw0 = sbits[cl][0], sw1 = sbits[cl][1], sw2 = sbits[cl][2], sw3 = sbits[cl][3];
    #pragma unroll
    for (int i = 0; i < 16; ++i){
      int n = (tid >> 4) + 16 * i;
      int hh = n >> 4, ww = n & 15;
      float acc = cbv;
      #pragma unroll
      for (int dy = -1; dy <= 1; ++dy){
        int yy = hh + dy; if ((unsigned)yy >= 16u) continue;
        #pragma unroll
        for (int dx = -1; dx <= 1; ++dx){
          int xx = ww + dx; if ((unsigned)xx >= 16u) continue;
          int p = yy * 16 + xx;
          u64 word = (p < 64) ? sw0 : (p < 128) ? sw1 : (p < 192) ? sw2 : sw3;
          if ((word >> (p & 63)) & 1ull) acc += cwv[(dy + 1) * 3 + (dx + 1)];
        }
      }
      float xv = xs[cl * 260 + n];
      xt[(((size_t)t * 16 + bb) * 256 + n) * 512 + c0 + cl] = xv + acc;
    }
    __syncthreads();
  }
}

// ---------------- fused LayerNorm (over C) + LIF (over T) -> bf16 spikes ----------------
__global__ __launch_bounds__(256) void ln_lif_kernel(const float* __restrict__ xt,
    const float* __restrict__ g, const float* __restrict__ be,
    const float* __restrict__ lifw, int lidx, unsigned short* __restrict__ spk){
  int bn = blockIdx.x; int tid = threadIdx.x;
  int c0 = tid * 2;
  __shared__ float red[256];
  float D = sigmoidf_(lifw[lidx]);
  float g0 = g[c0], g1 = g[c0 + 1];
  float b0 = be[c0], b1 = be[c0 + 1];
  float v0 = 0.f, v1 = 0.f;
  for (int t = 0; t < T_; ++t){
    size_t base = ((size_t)t * 4096 + bn) * 512;
    float x0 = xt[base + c0], x1 = xt[base + c0 + 1];
    red[tid] = x0 + x1; __syncthreads();
    for (int st = 128; st > 0; st >>= 1){ if (tid < st) red[tid] += red[tid + st]; __syncthreads(); }
    float mean = red[0] * (1.f / 512.f); __syncthreads();
    float d0 = x0 - mean, d1 = x1 - mean;
    red[tid] = d0 * d0 + d1 * d1; __syncthreads();
    for (int st = 128; st > 0; st >>= 1){ if (tid < st) red[tid] += red[tid + st]; __syncthreads(); }
    float var = red[0] * (1.f / 512.f); __syncthreads();
    float inv = 1.f / sqrtf(var + 1e-5f);
    float y0 = d0 * inv * g0 + b0;
    float y1 = d1 * inv * g1 + b1;
    v0 = v0 + (y0 - v0) * D; bool s0 = v0 >= 1.f;
    v1 = v1 + (y1 - v1) * D; bool s1 = v1 >= 1.f;
    spk[base + c0]     = s0 ? (unsigned short)0x3F80u : (unsigned short)0u;
    spk[base + c0 + 1] = s1 ? (unsigned short)0x3F80u : (unsigned short)0u;
    v0 = s0 ? 0.f : v0; v1 = s1 ? 0.f : v1;
  }
}

// ------- LIF over [16384,512] f32 pre-acts -> bit-packed spikes [16384,8] u64 -------
__global__ __launch_bounds__(256) void lif_pack_kernel(const float* __restrict__ in,
    u64* __restrict__ bits, const float* __restrict__ lifw, int lidx){
  int tid = blockIdx.x * 256 + threadIdx.x;      // 0 .. 4096*512-1
  int j = tid & 511; int bn = tid >> 9;
  int lane = threadIdx.x & 63; int wj = j >> 6;
  float D = sigmoidf_(lifw[lidx]);
  float v = 0.f;
  #pragma unroll
  for (int t = 0; t < T_; ++t){
    int m = t * 4096 + bn;
    float xv = in[(size_t)m * 512 + j];
    v = v + (xv - v) * D;
    bool sp = v >= 1.f;
    u64 bal = __ballot(sp);
    if (lane == 0) bits[(size_t)m * 8 + wj] = bal;
    v = sp ? 0.f : v;
  }
}

// ------- LIF over [16384,512] f32 pre-acts -> bf16 spikes [16384,512] -------
__global__ __launch_bounds__(256) void lif_spike_kernel(const float* __restrict__ in,
    unsigned short* __restrict__ out, const float* __restrict__ lifw, int lidx){
  int tid = blockIdx.x * 256 + threadIdx.x;
  int j = tid & 511; int bn = tid >> 9;
  float D = sigmoidf_(lifw[lidx]);
  float v = 0.f;
  #pragma unroll
  for (int t = 0; t < T_; ++t){
    int m = t * 4096 + bn;
    float xv = in[(size_t)m * 512 + j];
    v = v + (xv - v) * D;
    bool sp = v >= 1.f;
    out[(size_t)m * 512 + j] = sp ? (unsigned short)0x3F80u : (unsigned short)0u;
    v = sp ? 0.f : v;
  }
}

// ---- NT GEMM, split-bf16 weights, global_load_lds staging ----
// out[m,n] = sum_k A[m,k]*(Whi+Wlo)[n,k] (+bias)(+resid); A bf16 spikes, out f32
__global__ __launch_bounds__(256) void gemm_nt_kernel(
    const unsigned short* __restrict__ A, int lda,
    const unsigned short* __restrict__ Whi, const unsigned short* __restrict__ Wlo, int ldw,
    const float* __restrict__ bias, const float* __restrict__ resid,
    float* __restrict__ out, int ldo, int K){
  __shared__ __align__(16) unsigned short As[128 * 32];
  __shared__ __align__(16) unsigned short Bh[128 * 32];
  __shared__ __align__(16) unsigned short Bl[128 * 32];
  int m0 = blockIdx.x * 128, n0 = blockIdx.y * 128;
  int tid = threadIdx.x; int lane = tid & 63, wid = tid >> 6;
  int wm = (wid >> 1) * 64, wn = (wid & 1) * 64;
  int lm = lane & 15, lk = (lane >> 4) * 8;
  int r4 = lane >> 2, c8 = (lane & 3) * 8;
  int w16 = wid * 16;
  const unsigned short* pa0 = A   + (size_t)(m0 + w16 + r4) * lda + c8;
  const unsigned short* pa1 = pa0 + (size_t)64 * lda;
  const unsigned short* ph0 = Whi + (size_t)(n0 + w16 + r4) * ldw + c8;
  const unsigned short* ph1 = ph0 + (size_t)64 * ldw;
  const unsigned short* pl0 = Wlo + (size_t)(n0 + w16 + r4) * ldw + c8;
  const unsigned short* pl1 = pl0 + (size_t)64 * ldw;
  int lofs = __builtin_amdgcn_readfirstlane(w16 * 32);   // u16 elements
  unsigned short* lA0 = As + lofs; unsigned short* lA1 = As + 2048 + lofs;
  unsigned short* lH0 = Bh + lofs; unsigned short* lH1 = Bh + 2048 + lofs;
  unsigned short* lL0 = Bl + lofs; unsigned short* lL1 = Bl + 2048 + lofs;
  floatx4 acc[4][4];
  #pragma unroll
  for (int i = 0; i < 4; ++i)
    #pragma unroll
    for (int j = 0; j < 4; ++j){ acc[i][j][0] = 0.f; acc[i][j][1] = 0.f; acc[i][j][2] = 0.f; acc[i][j][3] = 0.f; }

  for (int kb = 0; kb < K; kb += 32){
    gll16(pa0 + kb, lA0); gll16(pa1 + kb, lA1);
    gll16(ph0 + kb, lH0); gll16(ph1 + kb, lH1);
    gll16(pl0 + kb, lL0); gll16(pl1 + kb, lL1);
    __syncthreads();
    short8 af[4], bh[4], bl[4];
    #pragma unroll
    for (int im = 0; im < 4; ++im) af[im] = *(const short8*)(&As[(wm + im * 16 + lm) * 32 + lk]);
    #pragma unroll
    for (int in = 0; in < 4; ++in){
      bh[in] = *(const short8*)(&Bh[(wn + in * 16 + lm) * 32 + lk]);
      bl[in] = *(const short8*)(&Bl[(wn + in * 16 + lm) * 32 + lk]);
    }
    #pragma unroll
    for (int im = 0; im < 4; ++im)
      #pragma unroll
      for (int in = 0; in < 4; ++in){
        acc[im][in] = __builtin_amdgcn_mfma_f32_16x16x32_bf16(af[im], bh[in], acc[im][in], 0, 0, 0);
        acc[im][in] = __builtin_amdgcn_mfma_f32_16x16x32_bf16(af[im], bl[in], acc[im][in], 0, 0, 0);
      }
    __syncthreads();
  }
  #pragma unroll
  for (int im = 0; im < 4; ++im){
    int row0 = m0 + wm + im * 16 + ((lane >> 4) << 2);
    #pragma unroll
    for (int in = 0; in < 4; ++in){
      int col = n0 + wn + in * 16 + lm;
      float bv = bias ? bias[col] : 0.f;
      #pragma unroll
      for (int r = 0; r < 4; ++r){
        size_t idx = (size_t)(row0 + r) * ldo + col;
        float v = acc[im][in][r] + bv;
        if (resid) v += resid[idx];
        out[idx] = v;
      }
    }
  }
}

// ---- spiking linear attention per (t,b,h) from bit-packed spikes: a = q @ (k^T v) * 0.125 ----
__global__ __launch_bounds__(256) void attn_kernel(const u64* __restrict__ bits,
    float* __restrict__ aout){
  int tbh = blockIdx.x;                          // 512
  int h = tbh & 7, b = (tbh >> 3) & 15, t = tbh >> 7;
  int m0 = t * 4096 + b * 256;
  int tid = threadIdx.x;
  __shared__ u64 QW[256], KW[256], VW[256];
  __shared__ u64 kbt[64][4], vbt[64][4];
  __shared__ float kvm[64][64];
  {
    size_t base = (size_t)(m0 + tid) * 8 + h;
    QW[tid] = bits[base];
    KW[tid] = bits[131072 + base];
    VW[tid] = bits[262144 + base];
  }
  __syncthreads();
  {
    int i = tid & 63, w = tid >> 6;
    const u64* kwp = &KW[w * 64];
    const u64* vwp = &VW[w * 64];
    u64 bk = 0, bv = 0;
    for (int nn = 0; nn < 64; ++nn){
      bk |= ((kwp[nn] >> i) & 1ull) << nn;
      bv |= ((vwp[nn] >> i) & 1ull) << nn;
    }
    kbt[i][w] = bk; vbt[i][w] = bv;
  }
  __syncthreads();
  #pragma unroll
  for (int e = 0; e < 16; ++e){
    int idx = tid * 16 + e;
    int i = idx >> 6, j = idx & 63;
    int cnt = __popcll(kbt[i][0] & vbt[j][0]) + __popcll(kbt[i][1] & vbt[j][1])
            + __popcll(kbt[i][2] & vbt[j][2]) + __popcll(kbt[i][3] & vbt[j][3]);
    kvm[i][j] = (float)cnt;
  }
  __syncthreads();
  {
    u64 bq = QW[tid];
    floatx4 acc[16];
    #pragma unroll
    for (int jj = 0; jj < 16; ++jj){ acc[jj][0] = 0.f; acc[jj][1] = 0.f; acc[jj][2] = 0.f; acc[jj][3] = 0.f; }
    for (int i = 0; i < 64; ++i){
      float qf = (float)((bq >> i) & 1ull);
      const floatx4* row = (const floatx4*)(&kvm[i][0]);
      #pragma unroll
      for (int jj = 0; jj < 16; ++jj) acc[jj] += row[jj] * qf;
    }
    float* orow = aout + (size_t)(m0 + tid) * 512 + h * 64;
    #pragma unroll
    for (int jj = 0; jj < 16; ++jj)
      *(floatx4*)(orow + jj * 4) = acc[jj] * 0.125f;
  }
}

// ---------------- final transpose [T,B,N,C] f32 -> [T,B,C,H,W] f32 ----------------
__global__ __launch_bounds__(256) void out_kernel(const float* __restrict__ xt,
    float* __restrict__ out){
  int o = blockIdx.x * 256 + threadIdx.x;
  int n = o & 255; int c = (o >> 8) & 511; int tb = o >> 17;
  out[o] = xt[((size_t)(tb * 256 + n)) * 512 + c];
}

extern "C" void kernel_launch(void* const* d_in, const int* in_sizes, int n_in,
                              void* d_out, int out_size, void* d_ws, size_t ws_size,
                              hipStream_t stream){
  const float* x     = (const float*)d_in[0];
  const float* convw = (const float*)d_in[1];
  const float* convb = (const float*)d_in[2];
  const float* ln1g  = (const float*)d_in[3];
  const float* ln1b  = (const float*)d_in[4];
  const float* qkvw  = (const float*)d_in[5];
  const float* projw = (const float*)d_in[6];
  const float* projb = (const float*)d_in[7];
  const float* ln2g  = (const float*)d_in[8];
  const float* ln2b  = (const float*)d_in[9];
  const float* fc1w  = (const float*)d_in[10];
  const float* fc1b  = (const float*)d_in[11];
  const float* fc2w  = (const float*)d_in[12];
  const float* fc2b  = (const float*)d_in[13];
  const float* lifw  = (const float*)d_in[14];
  float* outp = (float*)d_out;

  // workspace layout (total ~116.4 MB)
  char* wsb = (char*)d_ws;
  float* XT           = (float*)wsb;                            // [16384,512] f32   33.5 MB
  float* CH           = (float*)(wsb + 33554432);               // [16384,512] f32   33.5 MB
  unsigned short* SPK = (unsigned short*)(wsb + 67108864);      // [16384,512] bf16  16.8 MB
  unsigned short* HC  = (unsigned short*)(wsb + 83886080);      // [16384,512] bf16  16.8 MB
  unsigned short* WHI = (unsigned short*)(wsb + 100663296);     // 3,145,728 bf16     6.3 MB
  unsigned short* WLO = (unsigned short*)(wsb + 106954752);     // 3,145,728 bf16     6.3 MB
  u64* QBITS          = (u64*)(wsb + 113246208);                // [3,16384,8] u64    3.1 MB
  const int OFF_QKV = 0, OFF_PROJ = 786432, OFF_FC1 = 1048576, OFF_FC2 = 2097152;

  // 0. split weights into bf16 hi/lo
  wsplit_kernel<<<12288, 256, 0, stream>>>(qkvw, projw, fc1w, fc2w, WHI, WLO);
  // 1+2. fused lif(x) + depthwise conv + residual + transpose -> XT [T,B,N,C]
  conv_lif_kernel<<<512, 256, 0, stream>>>(x, convw, convb, lifw, XT);
  // 3. h1 = lif(LN1(xt)) -> SPK
  ln_lif_kernel<<<4096, 256, 0, stream>>>(XT, ln1g, ln1b, lifw, 1, SPK);
  // 4. qkv = h1 @ qkv_w^T -> LIF -> bit-packed q,k,v
  for (int p = 0; p < 3; ++p){
    gemm_nt_kernel<<<dim3(128, 4), 256, 0, stream>>>(SPK, 512,
        WHI + OFF_QKV + (size_t)p * 262144, WLO + OFF_QKV + (size_t)p * 262144, 512,
        nullptr, nullptr, CH, 512, 512);
    lif_pack_kernel<<<8192, 256, 0, stream>>>(CH, QBITS + (size_t)p * 131072, lifw, 2 + p);
  }
  // 5. linear attention -> CH (f32 pre-acts)
  attn_kernel<<<512, 256, 0, stream>>>(QBITS, CH);
  // 6. a_s = lif(a) -> SPK
  lif_spike_kernel<<<8192, 256, 0, stream>>>(CH, SPK, lifw, 5);
  // 7. xt += a_s @ proj_w^T + proj_b
  gemm_nt_kernel<<<dim3(128, 4), 256, 0, stream>>>(SPK, 512,
      WHI + OFF_PROJ, WLO + OFF_PROJ, 512, projb, XT, XT, 512, 512);
  // 8. h2 = lif(LN2(xt)) -> SPK
  ln_lif_kernel<<<4096, 256, 0, stream>>>(XT, ln2g, ln2b, lifw, 6, SPK);
  // 9. MLP, K-chunked over hidden: per chunk fc1 -> LIF -> fc2-accumulate into XT
  for (int hcb = 0; hcb < 4; ++hcb){
    gemm_nt_kernel<<<dim3(128, 4), 256, 0, stream>>>(SPK, 512,
        WHI + OFF_FC1 + (size_t)hcb * 262144, WLO + OFF_FC1 + (size_t)hcb * 262144, 512,
        fc1b + hcb * 512, nullptr, CH, 512, 512);
    lif_spike_kernel<<<8192, 256, 0, stream>>>(CH, HC, lifw, 7);
    gemm_nt_kernel<<<dim3(128, 4), 256, 0, stream>>>(HC, 512,
        WHI + OFF_FC2 + hcb * 512, WLO + OFF_FC2 + hcb * 512, 2048,
        (hcb == 0 ? fc2b : nullptr), XT, XT, 512, 512);
  }
  // 10. transpose back to [T,B,C,H,W] f32
  out_kernel<<<32768, 256, 0, stream>>>(XT, outp);
}

// Round 5
// 614.126 us; speedup vs baseline: 1.6202x; 1.1395x over previous
//
#include <hip/hip_runtime.h>

typedef unsigned long long u64;
typedef unsigned int u32;
typedef float  floatx4 __attribute__((ext_vector_type(4)));
typedef short  short8  __attribute__((ext_vector_type(8)));

#define T_ 4
#define B_ 16
#define C_ 512
#define N_ 256
#define M_ 16384   // T*B*N

static __device__ __forceinline__ float b2f(unsigned short u){
  union { unsigned int i; float f; } x; x.i = ((unsigned int)u) << 16; return x.f;
}
static __device__ __forceinline__ unsigned short f2b(float f){
  unsigned int u = __float_as_uint(f);
  unsigned int r = (u + 0x7FFFu + ((u >> 16) & 1u)) >> 16;
  return (unsigned short)r;
}
static __device__ __forceinline__ float sigmoidf_(float x){ return 1.f / (1.f + expf(-x)); }

// async global->LDS, 16 B per lane; lds base must be wave-uniform
static __device__ __forceinline__ void gll16(const void* g, void* l){
  __builtin_amdgcn_global_load_lds(
      (const __attribute__((address_space(1))) void*)g,
      (__attribute__((address_space(3))) void*)l, 16, 0, 0);
}

// ------- split all weights into bf16 hi + bf16 lo (concatenated qkv|proj|fc1|fc2) -------
__global__ __launch_bounds__(256) void wsplit_kernel(const float* __restrict__ qkvw,
    const float* __restrict__ projw, const float* __restrict__ fc1w,
    const float* __restrict__ fc2w, unsigned short* __restrict__ hi,
    unsigned short* __restrict__ lo){
  int i = blockIdx.x * 256 + threadIdx.x;        // 0 .. 3,145,727
  const float* src; int off;
  if (i < 786432)      { src = qkvw; off = i; }
  else if (i < 1048576){ src = projw; off = i - 786432; }
  else if (i < 2097152){ src = fc1w;  off = i - 1048576; }
  else                 { src = fc2w;  off = i - 2097152; }
  float f = src[off];
  unsigned short h = f2b(f);
  float r = f - b2f(h);
  hi[i] = h; lo[i] = f2b(r);
}

// ---- FUSED: lif(x) + depthwise 3x3 conv + residual + transpose to [T,B,N,C] f32 ----
__global__ __launch_bounds__(256) void conv_lif_kernel(const float* __restrict__ x,
    const float* __restrict__ cw, const float* __restrict__ cb,
    const float* __restrict__ lifw, float* __restrict__ xt){
  __shared__ __align__(16) float xs[16 * 260];
  __shared__ u64 sbits[16][5];
  int bb = blockIdx.x & 15, cg = blockIdx.x >> 4;
  int c0 = cg * 16;
  int tid = threadIdx.x;
  int lane = tid & 63, w = tid >> 6;
  int cl = tid & 15;
  float D = sigmoidf_(lifw[0]);
  float cwv[9];
  #pragma unroll
  for (int j = 0; j < 9; ++j) cwv[j] = cw[(c0 + cl) * 9 + j];
  float cbv = cb[c0 + cl];
  float v[16];
  #pragma unroll
  for (int k = 0; k < 16; ++k) v[k] = 0.f;

  for (int t = 0; t < T_; ++t){
    #pragma unroll
    for (int j = 0; j < 4; ++j){
      int kk = __builtin_amdgcn_readfirstlane(w + 4 * j);
      const float* grow = x + (((size_t)t * 16 + bb) * 512 + c0 + kk) * 256 + lane * 4;
      gll16(grow, &xs[kk * 260]);
    }
    __syncthreads();
    #pragma unroll
    for (int k = 0; k < 16; ++k){
      float xv = xs[k * 260 + tid];
      v[k] = v[k] + (xv - v[k]) * D;
      bool sp = v[k] >= 1.f;
      u64 bal = __ballot(sp);
      if (lane == 0) sbits[k][w] = bal;
      v[k] = sp ? 0.f : v[k];
    }
    __syncthreads();
    u64 sw0 = sbits[cl][0], sw1 = sbits[cl][1], sw2 = sbits[cl][2], sw3 = sbits[cl][3];
    #pragma unroll
    for (int i = 0; i < 16; ++i){
      int n = (tid >> 4) + 16 * i;
      int hh = n >> 4, ww = n & 15;
      float acc = cbv;
      #pragma unroll
      for (int dy = -1; dy <= 1; ++dy){
        int yy = hh + dy; if ((unsigned)yy >= 16u) continue;
        #pragma unroll
        for (int dx = -1; dx <= 1; ++dx){
          int xx = ww + dx; if ((unsigned)xx >= 16u) continue;
          int p = yy * 16 + xx;
          u64 word = (p < 64) ? sw0 : (p < 128) ? sw1 : (p < 192) ? sw2 : sw3;
          if ((word >> (p & 63)) & 1ull) acc += cwv[(dy + 1) * 3 + (dx + 1)];
        }
      }
      float xv = xs[cl * 260 + n];
      xt[(((size_t)t * 16 + bb) * 256 + n) * 512 + c0 + cl] = xv + acc;
    }
    __syncthreads();
  }
}

// ------- fused LayerNorm (over C) + LIF (over T) -> bf16 spikes, shfl reductions -------
__global__ __launch_bounds__(256) void ln_lif_kernel(const float* __restrict__ xt,
    const float* __restrict__ g, const float* __restrict__ be,
    const float* __restrict__ lifw, int lidx, unsigned short* __restrict__ spk){
  int bn = blockIdx.x; int tid = threadIdx.x;
  int lane = tid & 63, wid = tid >> 6;
  int c0 = tid * 2;
  __shared__ float ps[8];
  float D = sigmoidf_(lifw[lidx]);
  float g0 = g[c0], g1 = g[c0 + 1];
  float b0 = be[c0], b1 = be[c0 + 1];
  float v0 = 0.f, v1 = 0.f;
  for (int t = 0; t < T_; ++t){
    size_t base = ((size_t)t * 4096 + bn) * 512;
    float x0 = xt[base + c0], x1 = xt[base + c0 + 1];
    float s = x0 + x1, q = x0 * x0 + x1 * x1;
    #pragma unroll
    for (int m = 32; m > 0; m >>= 1){
      s += __shfl_xor(s, m, 64);
      q += __shfl_xor(q, m, 64);
    }
    if (lane == 0){ ps[wid * 2] = s; ps[wid * 2 + 1] = q; }
    __syncthreads();
    float S = ps[0] + ps[2] + ps[4] + ps[6];
    float Q = ps[1] + ps[3] + ps[5] + ps[7];
    __syncthreads();
    float mean = S * (1.f / 512.f);
    float var = Q * (1.f / 512.f) - mean * mean;
    float inv = 1.f / sqrtf(var + 1e-5f);
    float y0 = (x0 - mean) * inv * g0 + b0;
    float y1 = (x1 - mean) * inv * g1 + b1;
    v0 = v0 + (y0 - v0) * D; bool s0 = v0 >= 1.f;
    v1 = v1 + (y1 - v1) * D; bool s1 = v1 >= 1.f;
    u32 pk = (s0 ? 0x3F80u : 0u) | (s1 ? 0x3F800000u : 0u);
    *(u32*)(spk + base + c0) = pk;
    v0 = s0 ? 0.f : v0; v1 = s1 ? 0.f : v1;
  }
}

// ---- NT GEMM, split-bf16 weights, t-restructured M-tiles, fused LIF epilogues ----
// M-tile rows r=0..127 map to global row g = (r>>5)*4096 + bn0 + (r&31)  (4 timesteps x 32 tokens)
// mode 0: xtio[g,col] += acc + bias  (resid accumulate in place)
// mode 1: LIF(lidx=2+part) -> bit-packed spikes to outBits (qkv)
// mode 2: LIF(lidx) + bias -> bf16 spikes to outSpk (fc1)
// mode 3: v = acc + xtio[g,col]; final transposed store to outF [T,B,C,H,W]
__global__ __launch_bounds__(256) void gemm_fused(
    const unsigned short* __restrict__ A, int lda,
    const unsigned short* __restrict__ Whi, const unsigned short* __restrict__ Wlo, int ldw,
    const float* __restrict__ bias,
    float* __restrict__ xtio, float* __restrict__ outF,
    u64* __restrict__ outBits, unsigned short* __restrict__ outSpk, int ldspk,
    int K, int mode, const float* __restrict__ lifw, int lidx){
  __shared__ __align__(16) unsigned short smem[12288];   // 24576 B: As|Bh|Bl, reused by epilogue
  unsigned short* As = smem;
  unsigned short* Bh = smem + 4096;
  unsigned short* Bl = smem + 8192;
  int bn0 = blockIdx.x * 32;
  int n0  = blockIdx.y * 128;
  int tid = threadIdx.x, lane = tid & 63, wid = tid >> 6;
  int wm = (wid >> 1) * 64, wn = (wid & 1) * 64;
  int lm = lane & 15, quad = lane >> 4;
  int r4 = lane >> 2;
  int swz = ((lane & 3) ^ ((lane >> 3) & 3)) * 8;       // XOR bank swizzle (2-way = free)
  int rA0 = wid * 16 + r4, rA1 = rA0 + 64;
  size_t ga0 = (size_t)((rA0 >> 5) * 4096 + bn0 + (rA0 & 31));
  size_t ga1 = (size_t)((rA1 >> 5) * 4096 + bn0 + (rA1 & 31));
  const unsigned short* pa0 = A   + ga0 * lda + swz;
  const unsigned short* pa1 = A   + ga1 * lda + swz;
  const unsigned short* ph0 = Whi + (size_t)(n0 + rA0) * ldw + swz;
  const unsigned short* ph1 = Whi + (size_t)(n0 + rA1) * ldw + swz;
  const unsigned short* pl0 = Wlo + (size_t)(n0 + rA0) * ldw + swz;
  const unsigned short* pl1 = Wlo + (size_t)(n0 + rA1) * ldw + swz;
  int lofs = __builtin_amdgcn_readfirstlane(wid * 512);
  int sx = (quad ^ ((lm >> 1) & 3)) << 3;               // read-side un-swizzle

  floatx4 acc[4][4];
  #pragma unroll
  for (int i = 0; i < 4; ++i)
    #pragma unroll
    for (int j = 0; j < 4; ++j){ acc[i][j][0]=0.f; acc[i][j][1]=0.f; acc[i][j][2]=0.f; acc[i][j][3]=0.f; }

  for (int kb = 0; kb < K; kb += 32){
    gll16(pa0 + kb, As + lofs); gll16(pa1 + kb, As + 2048 + lofs);
    gll16(ph0 + kb, Bh + lofs); gll16(ph1 + kb, Bh + 2048 + lofs);
    gll16(pl0 + kb, Bl + lofs); gll16(pl1 + kb, Bl + 2048 + lofs);
    __syncthreads();
    short8 af[4], bh[4], bl[4];
    #pragma unroll
    for (int im = 0; im < 4; ++im) af[im] = *(const short8*)(&As[(wm + im * 16 + lm) * 32 + sx]);
    #pragma unroll
    for (int in = 0; in < 4; ++in){
      bh[in] = *(const short8*)(&Bh[(wn + in * 16 + lm) * 32 + sx]);
      bl[in] = *(const short8*)(&Bl[(wn + in * 16 + lm) * 32 + sx]);
    }
    #pragma unroll
    for (int im = 0; im < 4; ++im)
      #pragma unroll
      for (int in = 0; in < 4; ++in){
        acc[im][in] = __builtin_amdgcn_mfma_f32_16x16x32_bf16(af[im], bh[in], acc[im][in], 0, 0, 0);
        acc[im][in] = __builtin_amdgcn_mfma_f32_16x16x32_bf16(af[im], bl[in], acc[im][in], 0, 0, 0);
      }
    __syncthreads();
  }

  if (mode == 0 || mode == 3){
    #pragma unroll
    for (int im = 0; im < 4; ++im){
      int tr0 = wm + im * 16 + quad * 4;
      #pragma unroll
      for (int in = 0; in < 4; ++in){
        int col = n0 + wn + in * 16 + lm;
        float bv = bias ? bias[col] : 0.f;
        #pragma unroll
        for (int r = 0; r < 4; ++r){
          int tr = tr0 + r;
          int t = tr >> 5; int bq = bn0 + (tr & 31);
          size_t gg = (size_t)t * 4096 + bq;
          float vv = acc[im][in][r] + bv + xtio[gg * 512 + col];
          if (mode == 0){
            xtio[gg * 512 + col] = vv;
          } else {
            int bb = bq >> 8, nn = bq & 255;
            outF[(((size_t)t * 16 + bb) * 512 + col) * 256 + nn] = vv;
          }
        }
      }
    }
    return;
  }

  // modes 1/2: LDS round-trip per 32-col chunk, LIF over t
  float* cbuf = (float*)smem;                      // [128][36] f32 = 18432 B
  u32* bits32 = (u32*)((char*)smem + 20480);       // 512 u32 (mode 1)
  int lix = (mode == 1) ? (2 + (n0 >> 9)) : lidx;
  float D = sigmoidf_(lifw[lix]);
  if (mode == 1){ bits32[tid] = 0; bits32[256 + tid] = 0; }
  for (int ch = 0; ch < 4; ++ch){
    __syncthreads();
    if (wn == (ch >> 1) * 64){
      int in0 = (ch & 1) * 2;
      #pragma unroll
      for (int ii = 0; ii < 2; ++ii){
        int in = in0 + ii;
        int colL = in * 16 + lm - (ch & 1) * 32;
        #pragma unroll
        for (int im = 0; im < 4; ++im){
          int tr0 = wm + im * 16 + quad * 4;
          #pragma unroll
          for (int r = 0; r < 4; ++r) cbuf[(tr0 + r) * 36 + colL] = acc[im][in][r];
        }
      }
    }
    __syncthreads();
    int bnl = tid >> 3, c4 = (tid & 7) * 4;
    float b4[4];
    #pragma unroll
    for (int j = 0; j < 4; ++j) b4[j] = bias ? bias[n0 + ch * 32 + c4 + j] : 0.f;
    float vv[4] = {0.f, 0.f, 0.f, 0.f};
    #pragma unroll
    for (int t = 0; t < 4; ++t){
      int row = t * 32 + bnl;
      u32 nib = 0;
      unsigned short sp4[4];
      #pragma unroll
      for (int j = 0; j < 4; ++j){
        float pre = cbuf[row * 36 + c4 + j] + b4[j];
        vv[j] = vv[j] + (pre - vv[j]) * D;
        bool s = vv[j] >= 1.f;
        nib |= (u32)s << j;
        sp4[j] = s ? (unsigned short)0x3F80u : (unsigned short)0u;
        vv[j] = s ? 0.f : vv[j];
      }
      if (mode == 1){
        if (nib) atomicOr(&bits32[(row * 2 + (ch >> 1)) * 2 + (ch & 1)], nib << c4);
      } else {
        size_t gg = (size_t)t * 4096 + bn0 + bnl;
        u32 lo = (u32)sp4[0] | ((u32)sp4[1] << 16);
        u32 hi = (u32)sp4[2] | ((u32)sp4[3] << 16);
        u32* dst = (u32*)(outSpk + gg * ldspk + n0 + ch * 32 + c4);
        dst[0] = lo; dst[1] = hi;
      }
    }
  }
  if (mode == 1){
    __syncthreads();
    int t = tid >> 6, bnl = (tid >> 1) & 31, j = tid & 1;
    size_t m = (size_t)t * 4096 + bn0 + bnl;
    int part = n0 >> 9, wbase = (n0 & 511) >> 6;
    int idx = ((t * 32 + bnl) * 2 + j) * 2;
    u64 wv = (u64)bits32[idx] | ((u64)bits32[idx + 1] << 32);
    outBits[(size_t)part * 131072 + m * 8 + wbase + j] = wv;
  }
}

// ---- spiking linear attention + LIF, per (b,h), t-loop inside: a_s spikes -> SPK ----
__global__ __launch_bounds__(256) void attn_lif_kernel(const u64* __restrict__ bits,
    unsigned short* __restrict__ spk, const float* __restrict__ lifw){
  int bh = blockIdx.x;                           // 128
  int h = bh & 7, b = bh >> 3;
  int tid = threadIdx.x;
  float D = sigmoidf_(lifw[5]);
  __shared__ u64 QW[256], KW[256], VW[256];
  __shared__ u64 kbt[64][4], vbt[64][4];
  __shared__ float kvm[64][64];
  float v[64];
  #pragma unroll
  for (int j = 0; j < 64; ++j) v[j] = 0.f;
  for (int t = 0; t < T_; ++t){
    int m0 = t * 4096 + b * 256;
    size_t base = (size_t)(m0 + tid) * 8 + h;
    QW[tid] = bits[base];
    KW[tid] = bits[131072 + base];
    VW[tid] = bits[262144 + base];
    __syncthreads();
    {
      int i = tid & 63, w = tid >> 6;
      const u64* kwp = &KW[w * 64];
      const u64* vwp = &VW[w * 64];
      u64 bk = 0, bv = 0;
      for (int nn = 0; nn < 64; ++nn){
        bk |= ((kwp[nn] >> i) & 1ull) << nn;
        bv |= ((vwp[nn] >> i) & 1ull) << nn;
      }
      kbt[i][w] = bk; vbt[i][w] = bv;
    }
    __syncthreads();
    #pragma unroll
    for (int e = 0; e < 16; ++e){
      int idx = tid * 16 + e;
      int i = idx >> 6, j = idx & 63;
      int cnt = __popcll(kbt[i][0] & vbt[j][0]) + __popcll(kbt[i][1] & vbt[j][1])
              + __popcll(kbt[i][2] & vbt[j][2]) + __popcll(kbt[i][3] & vbt[j][3]);
      kvm[i][j] = (float)cnt;
    }
    __syncthreads();
    {
      u64 bq = QW[tid];
      floatx4 acc[16];
      #pragma unroll
      for (int jj = 0; jj < 16; ++jj){ acc[jj][0]=0.f; acc[jj][1]=0.f; acc[jj][2]=0.f; acc[jj][3]=0.f; }
      for (int i = 0; i < 64; ++i){
        float qf = (float)((bq >> i) & 1ull);
        const floatx4* row = (const floatx4*)(&kvm[i][0]);
        #pragma unroll
        for (int jj = 0; jj < 16; ++jj) acc[jj] += row[jj] * qf;
      }
      u32* orow = (u32*)(spk + (size_t)(m0 + tid) * 512 + h * 64);
      #pragma unroll
      for (int p = 0; p < 32; ++p){
        int j0 = 2 * p, j1 = 2 * p + 1;
        float a0 = acc[j0 >> 2][j0 & 3] * 0.125f;
        float a1 = acc[j1 >> 2][j1 & 3] * 0.125f;
        v[j0] = v[j0] + (a0 - v[j0]) * D; bool s0 = v[j0] >= 1.f; v[j0] = s0 ? 0.f : v[j0];
        v[j1] = v[j1] + (a1 - v[j1]) * D; bool s1 = v[j1] >= 1.f; v[j1] = s1 ? 0.f : v[j1];
        orow[p] = (s0 ? 0x3F80u : 0u) | (s1 ? 0x3F800000u : 0u);
      }
    }
    __syncthreads();
  }
}

extern "C" void kernel_launch(void* const* d_in, const int* in_sizes, int n_in,
                              void* d_out, int out_size, void* d_ws, size_t ws_size,
                              hipStream_t stream){
  const float* x     = (const float*)d_in[0];
  const float* convw = (const float*)d_in[1];
  const float* convb = (const float*)d_in[2];
  const float* ln1g  = (const float*)d_in[3];
  const float* ln1b  = (const float*)d_in[4];
  const float* qkvw  = (const float*)d_in[5];
  const float* projw = (const float*)d_in[6];
  const float* projb = (const float*)d_in[7];
  const float* ln2g  = (const float*)d_in[8];
  const float* ln2b  = (const float*)d_in[9];
  const float* fc1w  = (const float*)d_in[10];
  const float* fc1b  = (const float*)d_in[11];
  const float* fc2w  = (const float*)d_in[12];
  const float* fc2b  = (const float*)d_in[13];
  const float* lifw  = (const float*)d_in[14];
  float* outp = (float*)d_out;

  // workspace layout (total ~99.6 MB)
  char* wsb = (char*)d_ws;
  float* XT           = (float*)wsb;                           // [16384,512] f32    33.5 MB
  unsigned short* SPK = (unsigned short*)(wsb + 33554432);     // [16384,512] bf16   16.8 MB
  unsigned short* HC  = (unsigned short*)(wsb + 50331648);     // [16384,1024] bf16  33.5 MB
  unsigned short* WHI = (unsigned short*)(wsb + 83886080);     // 3,145,728 bf16      6.3 MB
  unsigned short* WLO = (unsigned short*)(wsb + 90177536);     // 3,145,728 bf16      6.3 MB
  u64* QBITS          = (u64*)(wsb + 96468992);                // [3,16384,8] u64     3.1 MB
  const int OFF_QKV = 0, OFF_PROJ = 786432, OFF_FC1 = 1048576, OFF_FC2 = 2097152;

  // 0. split weights into bf16 hi/lo
  wsplit_kernel<<<12288, 256, 0, stream>>>(qkvw, projw, fc1w, fc2w, WHI, WLO);
  // 1. fused lif(x) + depthwise conv + residual + transpose -> XT
  conv_lif_kernel<<<512, 256, 0, stream>>>(x, convw, convb, lifw, XT);
  // 2. h1 = lif(LN1(xt)) -> SPK
  ln_lif_kernel<<<4096, 256, 0, stream>>>(XT, ln1g, ln1b, lifw, 1, SPK);
  // 3. qkv GEMM + LIF -> bit-packed q,k,v (single dispatch, N=1536)
  gemm_fused<<<dim3(128, 12), 256, 0, stream>>>(SPK, 512,
      WHI + OFF_QKV, WLO + OFF_QKV, 512, nullptr,
      nullptr, nullptr, QBITS, nullptr, 0, 512, 1, lifw, 0);
  // 4. linear attention + LIF -> a_s spikes in SPK
  attn_lif_kernel<<<128, 256, 0, stream>>>(QBITS, SPK, lifw);
  // 5. xt += a_s @ proj_w^T + proj_b
  gemm_fused<<<dim3(128, 4), 256, 0, stream>>>(SPK, 512,
      WHI + OFF_PROJ, WLO + OFF_PROJ, 512, projb,
      XT, nullptr, nullptr, nullptr, 0, 512, 0, lifw, 0);
  // 6. h2 = lif(LN2(xt)) -> SPK
  ln_lif_kernel<<<4096, 256, 0, stream>>>(XT, ln2g, ln2b, lifw, 6, SPK);
  // 7. MLP in two 1024-wide hidden halves; last fc2 half writes final output transposed
  // half 0
  gemm_fused<<<dim3(128, 8), 256, 0, stream>>>(SPK, 512,
      WHI + OFF_FC1, WLO + OFF_FC1, 512, fc1b,
      nullptr, nullptr, nullptr, HC, 1024, 512, 2, lifw, 7);
  gemm_fused<<<dim3(128, 4), 256, 0, stream>>>(HC, 1024,
      WHI + OFF_FC2, WLO + OFF_FC2, 2048, fc2b,
      XT, nullptr, nullptr, nullptr, 0, 1024, 0, lifw, 0);
  // half 1
  gemm_fused<<<dim3(128, 8), 256, 0, stream>>>(SPK, 512,
      WHI + OFF_FC1 + 524288, WLO + OFF_FC1 + 524288, 512, fc1b + 1024,
      nullptr, nullptr, nullptr, HC, 1024, 512, 2, lifw, 7);
  gemm_fused<<<dim3(128, 4), 256, 0, stream>>>(HC, 1024,
      WHI + OFF_FC2 + 1024, WLO + OFF_FC2 + 1024, 2048, nullptr,
      XT, outp, nullptr, nullptr, 0, 1024, 3, lifw, 0);
}

// Round 6
// 496.811 us; speedup vs baseline: 2.0028x; 1.2361x over previous
//
#include <hip/hip_runtime.h>

typedef unsigned long long u64;
typedef unsigned int u32;
typedef float  floatx4 __attribute__((ext_vector_type(4)));
typedef short  short8  __attribute__((ext_vector_type(8)));

#define T_ 4
#define B_ 16
#define C_ 512
#define N_ 256
#define M_ 16384   // T*B*N

static __device__ __forceinline__ float b2f(unsigned short u){
  union { unsigned int i; float f; } x; x.i = ((unsigned int)u) << 16; return x.f;
}
static __device__ __forceinline__ unsigned short f2b(float f){
  unsigned int u = __float_as_uint(f);
  unsigned int r = (u + 0x7FFFu + ((u >> 16) & 1u)) >> 16;
  return (unsigned short)r;
}
static __device__ __forceinline__ float sigmoidf_(float x){ return 1.f / (1.f + expf(-x)); }

// async global->LDS, 16 B per lane; lds base must be wave-uniform
static __device__ __forceinline__ void gll16(const void* g, void* l){
  __builtin_amdgcn_global_load_lds(
      (const __attribute__((address_space(1))) void*)g,
      (__attribute__((address_space(3))) void*)l, 16, 0, 0);
}

// ------- split all weights into bf16 hi + bf16 lo (concatenated qkv|proj|fc1|fc2) -------
__global__ __launch_bounds__(256) void wsplit_kernel(const float* __restrict__ qkvw,
    const float* __restrict__ projw, const float* __restrict__ fc1w,
    const float* __restrict__ fc2w, unsigned short* __restrict__ hi,
    unsigned short* __restrict__ lo){
  int i = blockIdx.x * 256 + threadIdx.x;        // 0 .. 3,145,727
  const float* src; int off;
  if (i < 786432)      { src = qkvw; off = i; }
  else if (i < 1048576){ src = projw; off = i - 786432; }
  else if (i < 2097152){ src = fc1w;  off = i - 1048576; }
  else                 { src = fc2w;  off = i - 2097152; }
  float f = src[off];
  unsigned short h = f2b(f);
  float r = f - b2f(h);
  hi[i] = h; lo[i] = f2b(r);
}

// ---- FUSED: lif(x) + depthwise 3x3 conv + residual + transpose to [T,B,N,C] f32 ----
__global__ __launch_bounds__(256) void conv_lif_kernel(const float* __restrict__ x,
    const float* __restrict__ cw, const float* __restrict__ cb,
    const float* __restrict__ lifw, float* __restrict__ xt){
  __shared__ __align__(16) float xs[16 * 260];
  __shared__ u64 sbits[16][5];
  int bb = blockIdx.x & 15, cg = blockIdx.x >> 4;
  int c0 = cg * 16;
  int tid = threadIdx.x;
  int lane = tid & 63, w = tid >> 6;
  int cl = tid & 15;
  float D = sigmoidf_(lifw[0]);
  float cwv[9];
  #pragma unroll
  for (int j = 0; j < 9; ++j) cwv[j] = cw[(c0 + cl) * 9 + j];
  float cbv = cb[c0 + cl];
  float v[16];
  #pragma unroll
  for (int k = 0; k < 16; ++k) v[k] = 0.f;

  for (int t = 0; t < T_; ++t){
    #pragma unroll
    for (int j = 0; j < 4; ++j){
      int kk = __builtin_amdgcn_readfirstlane(w + 4 * j);
      const float* grow = x + (((size_t)t * 16 + bb) * 512 + c0 + kk) * 256 + lane * 4;
      gll16(grow, &xs[kk * 260]);
    }
    __syncthreads();
    #pragma unroll
    for (int k = 0; k < 16; ++k){
      float xv = xs[k * 260 + tid];
      v[k] = v[k] + (xv - v[k]) * D;
      bool sp = v[k] >= 1.f;
      u64 bal = __ballot(sp);
      if (lane == 0) sbits[k][w] = bal;
      v[k] = sp ? 0.f : v[k];
    }
    __syncthreads();
    u64 sw0 = sbits[cl][0], sw1 = sbits[cl][1], sw2 = sbits[cl][2], sw3 = sbits[cl][3];
    #pragma unroll
    for (int i = 0; i < 16; ++i){
      int n = (tid >> 4) + 16 * i;
      int hh = n >> 4, ww = n & 15;
      float acc = cbv;
      #pragma unroll
      for (int dy = -1; dy <= 1; ++dy){
        int yy = hh + dy; if ((unsigned)yy >= 16u) continue;
        #pragma unroll
        for (int dx = -1; dx <= 1; ++dx){
          int xx = ww + dx; if ((unsigned)xx >= 16u) continue;
          int p = yy * 16 + xx;
          u64 word = (p < 64) ? sw0 : (p < 128) ? sw1 : (p < 192) ? sw2 : sw3;
          if ((word >> (p & 63)) & 1ull) acc += cwv[(dy + 1) * 3 + (dx + 1)];
        }
      }
      float xv = xs[cl * 260 + n];
      xt[(((size_t)t * 16 + bb) * 256 + n) * 512 + c0 + cl] = xv + acc;
    }
    __syncthreads();
  }
}

// ------- fused LayerNorm (over C) + LIF (over T) -> bf16 spikes, shfl reductions -------
__global__ __launch_bounds__(256) void ln_lif_kernel(const float* __restrict__ xt,
    const float* __restrict__ g, const float* __restrict__ be,
    const float* __restrict__ lifw, int lidx, unsigned short* __restrict__ spk){
  int bn = blockIdx.x; int tid = threadIdx.x;
  int lane = tid & 63, wid = tid >> 6;
  int c0 = tid * 2;
  __shared__ float ps[8];
  float D = sigmoidf_(lifw[lidx]);
  float g0 = g[c0], g1 = g[c0 + 1];
  float b0 = be[c0], b1 = be[c0 + 1];
  float v0 = 0.f, v1 = 0.f;
  for (int t = 0; t < T_; ++t){
    size_t base = ((size_t)t * 4096 + bn) * 512;
    float x0 = xt[base + c0], x1 = xt[base + c0 + 1];
    float s = x0 + x1, q = x0 * x0 + x1 * x1;
    #pragma unroll
    for (int m = 32; m > 0; m >>= 1){
      s += __shfl_xor(s, m, 64);
      q += __shfl_xor(q, m, 64);
    }
    if (lane == 0){ ps[wid * 2] = s; ps[wid * 2 + 1] = q; }
    __syncthreads();
    float S = ps[0] + ps[2] + ps[4] + ps[6];
    float Q = ps[1] + ps[3] + ps[5] + ps[7];
    __syncthreads();
    float mean = S * (1.f / 512.f);
    float var = Q * (1.f / 512.f) - mean * mean;
    float inv = 1.f / sqrtf(var + 1e-5f);
    float y0 = (x0 - mean) * inv * g0 + b0;
    float y1 = (x1 - mean) * inv * g1 + b1;
    v0 = v0 + (y0 - v0) * D; bool s0 = v0 >= 1.f;
    v1 = v1 + (y1 - v1) * D; bool s1 = v1 >= 1.f;
    u32 pk = (s0 ? 0x3F80u : 0u) | (s1 ? 0x3F800000u : 0u);
    *(u32*)(spk + base + c0) = pk;
    v0 = s0 ? 0.f : v0; v1 = s1 ? 0.f : v1;
  }
}

// ------- LIF over [16384,512] f32 pre-acts -> bf16 spikes [16384,512] -------
__global__ __launch_bounds__(256) void lif_spike_kernel(const float* __restrict__ in,
    unsigned short* __restrict__ out, const float* __restrict__ lifw, int lidx){
  int tid = blockIdx.x * 256 + threadIdx.x;
  int j = tid & 511; int bn = tid >> 9;
  float D = sigmoidf_(lifw[lidx]);
  float v = 0.f;
  #pragma unroll
  for (int t = 0; t < T_; ++t){
    int m = t * 4096 + bn;
    float xv = in[(size_t)m * 512 + j];
    v = v + (xv - v) * D;
    bool sp = v >= 1.f;
    out[(size_t)m * 512 + j] = sp ? (unsigned short)0x3F80u : (unsigned short)0u;
    v = sp ? 0.f : v;
  }
}

// ---- NT GEMM, split-bf16 weights, t-restructured M-tiles, fused LIF epilogues ----
// M-tile rows r=0..127 map to global row g = (r>>5)*4096 + bn0 + (r&31)
// mode 0: xtio[g,col] += acc + bias
// mode 1: LIF(lidx=2+part) -> bit-packed spikes to outBits (qkv)
// mode 2: LIF(lidx) + bias -> bf16 spikes to outSpk (fc1)
// mode 3: v = acc + xtio[g,col]; final transposed store to outF [T,B,C,H,W]
__global__ __launch_bounds__(256) void gemm_fused(
    const unsigned short* __restrict__ A, int lda,
    const unsigned short* __restrict__ Whi, const unsigned short* __restrict__ Wlo, int ldw,
    const float* __restrict__ bias,
    float* __restrict__ xtio, float* __restrict__ outF,
    u64* __restrict__ outBits, unsigned short* __restrict__ outSpk, int ldspk,
    int K, int mode, const float* __restrict__ lifw, int lidx){
  __shared__ __align__(16) unsigned short smem[12288];
  unsigned short* As = smem;
  unsigned short* Bh = smem + 4096;
  unsigned short* Bl = smem + 8192;
  int bn0 = blockIdx.x * 32;
  int n0  = blockIdx.y * 128;
  int tid = threadIdx.x, lane = tid & 63, wid = tid >> 6;
  int wm = (wid >> 1) * 64, wn = (wid & 1) * 64;
  int lm = lane & 15, quad = lane >> 4;
  int r4 = lane >> 2;
  int swz = ((lane & 3) ^ ((lane >> 3) & 3)) * 8;
  int rA0 = wid * 16 + r4, rA1 = rA0 + 64;
  size_t ga0 = (size_t)((rA0 >> 5) * 4096 + bn0 + (rA0 & 31));
  size_t ga1 = (size_t)((rA1 >> 5) * 4096 + bn0 + (rA1 & 31));
  const unsigned short* pa0 = A   + ga0 * lda + swz;
  const unsigned short* pa1 = A   + ga1 * lda + swz;
  const unsigned short* ph0 = Whi + (size_t)(n0 + rA0) * ldw + swz;
  const unsigned short* ph1 = Whi + (size_t)(n0 + rA1) * ldw + swz;
  const unsigned short* pl0 = Wlo + (size_t)(n0 + rA0) * ldw + swz;
  const unsigned short* pl1 = Wlo + (size_t)(n0 + rA1) * ldw + swz;
  int lofs = __builtin_amdgcn_readfirstlane(wid * 512);
  int sx = (quad ^ ((lm >> 1) & 3)) << 3;

  floatx4 acc[4][4];
  #pragma unroll
  for (int i = 0; i < 4; ++i)
    #pragma unroll
    for (int j = 0; j < 4; ++j){ acc[i][j][0]=0.f; acc[i][j][1]=0.f; acc[i][j][2]=0.f; acc[i][j][3]=0.f; }

  for (int kb = 0; kb < K; kb += 32){
    gll16(pa0 + kb, As + lofs); gll16(pa1 + kb, As + 2048 + lofs);
    gll16(ph0 + kb, Bh + lofs); gll16(ph1 + kb, Bh + 2048 + lofs);
    gll16(pl0 + kb, Bl + lofs); gll16(pl1 + kb, Bl + 2048 + lofs);
    __syncthreads();
    short8 af[4], bh[4], bl[4];
    #pragma unroll
    for (int im = 0; im < 4; ++im) af[im] = *(const short8*)(&As[(wm + im * 16 + lm) * 32 + sx]);
    #pragma unroll
    for (int in = 0; in < 4; ++in){
      bh[in] = *(const short8*)(&Bh[(wn + in * 16 + lm) * 32 + sx]);
      bl[in] = *(const short8*)(&Bl[(wn + in * 16 + lm) * 32 + sx]);
    }
    #pragma unroll
    for (int im = 0; im < 4; ++im)
      #pragma unroll
      for (int in = 0; in < 4; ++in){
        acc[im][in] = __builtin_amdgcn_mfma_f32_16x16x32_bf16(af[im], bh[in], acc[im][in], 0, 0, 0);
        acc[im][in] = __builtin_amdgcn_mfma_f32_16x16x32_bf16(af[im], bl[in], acc[im][in], 0, 0, 0);
      }
    __syncthreads();
  }

  if (mode == 0 || mode == 3){
    #pragma unroll
    for (int im = 0; im < 4; ++im){
      int tr0 = wm + im * 16 + quad * 4;
      #pragma unroll
      for (int in = 0; in < 4; ++in){
        int col = n0 + wn + in * 16 + lm;
        float bv = bias ? bias[col] : 0.f;
        #pragma unroll
        for (int r = 0; r < 4; ++r){
          int tr = tr0 + r;
          int t = tr >> 5; int bq = bn0 + (tr & 31);
          size_t gg = (size_t)t * 4096 + bq;
          float vv = acc[im][in][r] + bv + xtio[gg * 512 + col];
          if (mode == 0){
            xtio[gg * 512 + col] = vv;
          } else {
            int bb = bq >> 8, nn = bq & 255;
            outF[(((size_t)t * 16 + bb) * 512 + col) * 256 + nn] = vv;
          }
        }
      }
    }
    return;
  }

  // modes 1/2: LDS round-trip per 32-col chunk, LIF over t
  float* cbuf = (float*)smem;
  u32* bits32 = (u32*)((char*)smem + 20480);
  int lix = (mode == 1) ? (2 + (n0 >> 9)) : lidx;
  float D = sigmoidf_(lifw[lix]);
  if (mode == 1){ bits32[tid] = 0; bits32[256 + tid] = 0; }
  for (int ch = 0; ch < 4; ++ch){
    __syncthreads();
    if (wn == (ch >> 1) * 64){
      int in0 = (ch & 1) * 2;
      #pragma unroll
      for (int ii = 0; ii < 2; ++ii){
        int in = in0 + ii;
        int colL = in * 16 + lm - (ch & 1) * 32;
        #pragma unroll
        for (int im = 0; im < 4; ++im){
          int tr0 = wm + im * 16 + quad * 4;
          #pragma unroll
          for (int r = 0; r < 4; ++r) cbuf[(tr0 + r) * 36 + colL] = acc[im][in][r];
        }
      }
    }
    __syncthreads();
    int bnl = tid >> 3, c4 = (tid & 7) * 4;
    float b4[4];
    #pragma unroll
    for (int j = 0; j < 4; ++j) b4[j] = bias ? bias[n0 + ch * 32 + c4 + j] : 0.f;
    float vv[4] = {0.f, 0.f, 0.f, 0.f};
    #pragma unroll
    for (int t = 0; t < 4; ++t){
      int row = t * 32 + bnl;
      u32 nib = 0;
      unsigned short sp4[4];
      #pragma unroll
      for (int j = 0; j < 4; ++j){
        float pre = cbuf[row * 36 + c4 + j] + b4[j];
        vv[j] = vv[j] + (pre - vv[j]) * D;
        bool s = vv[j] >= 1.f;
        nib |= (u32)s << j;
        sp4[j] = s ? (unsigned short)0x3F80u : (unsigned short)0u;
        vv[j] = s ? 0.f : vv[j];
      }
      if (mode == 1){
        if (nib) atomicOr(&bits32[(row * 2 + (ch >> 1)) * 2 + (ch & 1)], nib << c4);
      } else {
        size_t gg = (size_t)t * 4096 + bn0 + bnl;
        u32 lo = (u32)sp4[0] | ((u32)sp4[1] << 16);
        u32 hi = (u32)sp4[2] | ((u32)sp4[3] << 16);
        u32* dst = (u32*)(outSpk + gg * ldspk + n0 + ch * 32 + c4);
        dst[0] = lo; dst[1] = hi;
      }
    }
  }
  if (mode == 1){
    __syncthreads();
    int t = tid >> 6, bnl = (tid >> 1) & 31, j = tid & 1;
    size_t m = (size_t)t * 4096 + bn0 + bnl;
    int part = n0 >> 9, wbase = (n0 & 511) >> 6;
    int idx = ((t * 32 + bnl) * 2 + j) * 2;
    u64 wv = (u64)bits32[idx] | ((u64)bits32[idx + 1] << 32);
    outBits[(size_t)part * 131072 + m * 8 + wbase + j] = wv;
  }
}

// ---- attention pre-acts per (t,b,h): a = (q @ kvm) * 0.125 via MFMA, kvm by popcount ----
__global__ __launch_bounds__(256) void attn_a_kernel(const u64* __restrict__ bits,
    float* __restrict__ aout){
  int tbh = blockIdx.x;                          // 512 = t*128 + b*8 + h
  int h = tbh & 7, b = (tbh >> 3) & 15, t = tbh >> 7;
  int m0 = t * 4096 + b * 256;
  int tid = threadIdx.x, lane = tid & 63, wid = tid >> 6;
  __shared__ u64 QW[256], KW[256], VW[256];
  __shared__ u64 kbt[64][4], vbt[64][4];
  __shared__ __align__(16) unsigned short Bs[64 * 72];   // Bs[j][i] = kvm[i][j], pad 72
  {
    size_t base = (size_t)(m0 + tid) * 8 + h;
    QW[tid] = bits[base];
    KW[tid] = bits[131072 + base];
    VW[tid] = bits[262144 + base];
  }
  __syncthreads();
  {
    int i = tid & 63, w = tid >> 6;
    const u64* kwp = &KW[w * 64];
    const u64* vwp = &VW[w * 64];
    u64 bk = 0, bv = 0;
    for (int nn = 0; nn < 64; ++nn){
      bk |= ((kwp[nn] >> i) & 1ull) << nn;
      bv |= ((vwp[nn] >> i) & 1ull) << nn;
    }
    kbt[i][w] = bk; vbt[i][w] = bv;
  }
  __syncthreads();
  #pragma unroll
  for (int e = 0; e < 16; ++e){
    int idx = tid * 16 + e;
    int i = idx >> 6, j = idx & 63;
    int cnt = __popcll(kbt[i][0] & vbt[j][0]) + __popcll(kbt[i][1] & vbt[j][1])
            + __popcll(kbt[i][2] & vbt[j][2]) + __popcll(kbt[i][3] & vbt[j][3]);
    Bs[j * 72 + i] = f2b((float)cnt);            // exact: cnt <= 256
  }
  __syncthreads();
  // MFMA: a[n,j] = sum_i q[n,i] * Bs[j][i]
  int lm = lane & 15, quad = lane >> 4;
  int wm = wid * 64;
  u64 qw[4];
  #pragma unroll
  for (int im = 0; im < 4; ++im) qw[im] = QW[wm + im * 16 + lm];
  floatx4 acc[4][4];
  #pragma unroll
  for (int i = 0; i < 4; ++i)
    #pragma unroll
    for (int j = 0; j < 4; ++j){ acc[i][j][0]=0.f; acc[i][j][1]=0.f; acc[i][j][2]=0.f; acc[i][j][3]=0.f; }
  #pragma unroll
  for (int kb = 0; kb < 64; kb += 32){
    short8 af[4], bf[4];
    #pragma unroll
    for (int im = 0; im < 4; ++im){
      u32 byte = (u32)(qw[im] >> (kb + quad * 8)) & 0xFFu;
      short8 a;
      #pragma unroll
      for (int jj = 0; jj < 8; ++jj) a[jj] = ((byte >> jj) & 1u) ? (short)0x3F80 : (short)0;
      af[im] = a;
    }
    #pragma unroll
    for (int in = 0; in < 4; ++in)
      bf[in] = *(const short8*)(&Bs[(in * 16 + lm) * 72 + kb + quad * 8]);
    #pragma unroll
    for (int im = 0; im < 4; ++im)
      #pragma unroll
      for (int in = 0; in < 4; ++in)
        acc[im][in] = __builtin_amdgcn_mfma_f32_16x16x32_bf16(af[im], bf[in], acc[im][in], 0, 0, 0);
  }
  float* ob = aout + (size_t)m0 * 512 + h * 64;
  #pragma unroll
  for (int im = 0; im < 4; ++im){
    int nr0 = wm + im * 16 + quad * 4;
    #pragma unroll
    for (int in = 0; in < 4; ++in){
      int j = in * 16 + lm;
      #pragma unroll
      for (int r = 0; r < 4; ++r)
        ob[(size_t)(nr0 + r) * 512 + j] = acc[im][in][r] * 0.125f;
    }
  }
}

extern "C" void kernel_launch(void* const* d_in, const int* in_sizes, int n_in,
                              void* d_out, int out_size, void* d_ws, size_t ws_size,
                              hipStream_t stream){
  const float* x     = (const float*)d_in[0];
  const float* convw = (const float*)d_in[1];
  const float* convb = (const float*)d_in[2];
  const float* ln1g  = (const float*)d_in[3];
  const float* ln1b  = (const float*)d_in[4];
  const float* qkvw  = (const float*)d_in[5];
  const float* projw = (const float*)d_in[6];
  const float* projb = (const float*)d_in[7];
  const float* ln2g  = (const float*)d_in[8];
  const float* ln2b  = (const float*)d_in[9];
  const float* fc1w  = (const float*)d_in[10];
  const float* fc1b  = (const float*)d_in[11];
  const float* fc2w  = (const float*)d_in[12];
  const float* fc2b  = (const float*)d_in[13];
  const float* lifw  = (const float*)d_in[14];
  float* outp = (float*)d_out;

  // workspace layout (total ~99.6 MB)
  char* wsb = (char*)d_ws;
  float* XT           = (float*)wsb;                           // [16384,512] f32    33.5 MB
  unsigned short* SPK = (unsigned short*)(wsb + 33554432);     // [16384,512] bf16   16.8 MB
  float* AF32         = (float*)(wsb + 50331648);              // [16384,512] f32    33.5 MB (attn pre-acts)
  unsigned short* HC  = (unsigned short*)(wsb + 50331648);     // [16384,1024] bf16  (fc1 spikes, same region)
  unsigned short* WHI = (unsigned short*)(wsb + 83886080);     // 3,145,728 bf16      6.3 MB
  unsigned short* WLO = (unsigned short*)(wsb + 90177536);     // 3,145,728 bf16      6.3 MB
  u64* QBITS          = (u64*)(wsb + 96468992);                // [3,16384,8] u64     3.1 MB
  const int OFF_QKV = 0, OFF_PROJ = 786432, OFF_FC1 = 1048576, OFF_FC2 = 2097152;

  // 0. split weights into bf16 hi/lo
  wsplit_kernel<<<12288, 256, 0, stream>>>(qkvw, projw, fc1w, fc2w, WHI, WLO);
  // 1. fused lif(x) + depthwise conv + residual + transpose -> XT
  conv_lif_kernel<<<512, 256, 0, stream>>>(x, convw, convb, lifw, XT);
  // 2. h1 = lif(LN1(xt)) -> SPK
  ln_lif_kernel<<<4096, 256, 0, stream>>>(XT, ln1g, ln1b, lifw, 1, SPK);
  // 3. qkv GEMM + LIF -> bit-packed q,k,v (single dispatch, N=1536)
  gemm_fused<<<dim3(128, 12), 256, 0, stream>>>(SPK, 512,
      WHI + OFF_QKV, WLO + OFF_QKV, 512, nullptr,
      nullptr, nullptr, QBITS, nullptr, 0, 512, 1, lifw, 0);
  // 4a. attention pre-acts (MFMA, t-parallel) -> AF32
  attn_a_kernel<<<512, 256, 0, stream>>>(QBITS, AF32);
  // 4b. a_s = lif(a) -> SPK
  lif_spike_kernel<<<8192, 256, 0, stream>>>(AF32, SPK, lifw, 5);
  // 5. xt += a_s @ proj_w^T + proj_b
  gemm_fused<<<dim3(128, 4), 256, 0, stream>>>(SPK, 512,
      WHI + OFF_PROJ, WLO + OFF_PROJ, 512, projb,
      XT, nullptr, nullptr, nullptr, 0, 512, 0, lifw, 0);
  // 6. h2 = lif(LN2(xt)) -> SPK
  ln_lif_kernel<<<4096, 256, 0, stream>>>(XT, ln2g, ln2b, lifw, 6, SPK);
  // 7. MLP in two 1024-wide hidden halves; last fc2 half writes final output transposed
  gemm_fused<<<dim3(128, 8), 256, 0, stream>>>(SPK, 512,
      WHI + OFF_FC1, WLO + OFF_FC1, 512, fc1b,
      nullptr, nullptr, nullptr, HC, 1024, 512, 2, lifw, 7);
  gemm_fused<<<dim3(128, 4), 256, 0, stream>>>(HC, 1024,
      WHI + OFF_FC2, WLO + OFF_FC2, 2048, fc2b,
      XT, nullptr, nullptr, nullptr, 0, 1024, 0, lifw, 0);
  gemm_fused<<<dim3(128, 8), 256, 0, stream>>>(SPK, 512,
      WHI + OFF_FC1 + 524288, WLO + OFF_FC1 + 524288, 512, fc1b + 1024,
      nullptr, nullptr, nullptr, HC, 1024, 512, 2, lifw, 7);
  gemm_fused<<<dim3(128, 4), 256, 0, stream>>>(HC, 1024,
      WHI + OFF_FC2 + 1024, WLO + OFF_FC2 + 1024, 2048, nullptr,
      XT, outp, nullptr, nullptr, 0, 1024, 3, lifw, 0);
}

// Round 7
// 487.536 us; speedup vs baseline: 2.0409x; 1.0190x over previous
//
#include <hip/hip_runtime.h>

typedef unsigned long long u64;
typedef unsigned int u32;
typedef float  floatx4 __attribute__((ext_vector_type(4)));
typedef short  short8  __attribute__((ext_vector_type(8)));

#define T_ 4

static __device__ __forceinline__ float b2f(unsigned short u){
  union { unsigned int i; float f; } x; x.i = ((unsigned int)u) << 16; return x.f;
}
static __device__ __forceinline__ unsigned short f2b(float f){
  unsigned int u = __float_as_uint(f);
  unsigned int r = (u + 0x7FFFu + ((u >> 16) & 1u)) >> 16;
  return (unsigned short)r;
}
static __device__ __forceinline__ float sigmoidf_(float x){ return 1.f / (1.f + expf(-x)); }

static __device__ __forceinline__ void gll16(const void* g, void* l){
  __builtin_amdgcn_global_load_lds(
      (const __attribute__((address_space(1))) void*)g,
      (__attribute__((address_space(3))) void*)l, 16, 0, 0);
}

// ------- split all weights into bf16 hi + bf16 lo (concatenated qkv|proj|fc1|fc2) -------
__global__ __launch_bounds__(256) void wsplit_kernel(const float* __restrict__ qkvw,
    const float* __restrict__ projw, const float* __restrict__ fc1w,
    const float* __restrict__ fc2w, unsigned short* __restrict__ hi,
    unsigned short* __restrict__ lo){
  int i = blockIdx.x * 256 + threadIdx.x;
  const float* src; int off;
  if (i < 786432)      { src = qkvw; off = i; }
  else if (i < 1048576){ src = projw; off = i - 786432; }
  else if (i < 2097152){ src = fc1w;  off = i - 1048576; }
  else                 { src = fc2w;  off = i - 2097152; }
  float f = src[off];
  unsigned short h = f2b(f);
  float r = f - b2f(h);
  hi[i] = h; lo[i] = f2b(r);
}

// ---- FUSED: lif(x) + depthwise 3x3 conv + residual + transpose to [T,B,N,C] f32 ----
__global__ __launch_bounds__(256) void conv_lif_kernel(const float* __restrict__ x,
    const float* __restrict__ cw, const float* __restrict__ cb,
    const float* __restrict__ lifw, float* __restrict__ xt){
  __shared__ __align__(16) float xs[16 * 260];
  __shared__ u64 sbits[16][5];
  int bb = blockIdx.x & 15, cg = blockIdx.x >> 4;
  int c0 = cg * 16;
  int tid = threadIdx.x;
  int lane = tid & 63, w = tid >> 6;
  int cl = tid & 15;
  float D = sigmoidf_(lifw[0]);
  float cwv[9];
  #pragma unroll
  for (int j = 0; j < 9; ++j) cwv[j] = cw[(c0 + cl) * 9 + j];
  float cbv = cb[c0 + cl];
  float v[16];
  #pragma unroll
  for (int k = 0; k < 16; ++k) v[k] = 0.f;

  for (int t = 0; t < T_; ++t){
    #pragma unroll
    for (int j = 0; j < 4; ++j){
      int kk = __builtin_amdgcn_readfirstlane(w + 4 * j);
      const float* grow = x + (((size_t)t * 16 + bb) * 512 + c0 + kk) * 256 + lane * 4;
      gll16(grow, &xs[kk * 260]);
    }
    __syncthreads();
    #pragma unroll
    for (int k = 0; k < 16; ++k){
      float xv = xs[k * 260 + tid];
      v[k] = v[k] + (xv - v[k]) * D;
      bool sp = v[k] >= 1.f;
      u64 bal = __ballot(sp);
      if (lane == 0) sbits[k][w] = bal;
      v[k] = sp ? 0.f : v[k];
    }
    __syncthreads();
    u64 sw0 = sbits[cl][0], sw1 = sbits[cl][1], sw2 = sbits[cl][2], sw3 = sbits[cl][3];
    #pragma unroll
    for (int i = 0; i < 16; ++i){
      int n = (tid >> 4) + 16 * i;
      int hh = n >> 4, ww = n & 15;
      float acc = cbv;
      #pragma unroll
      for (int dy = -1; dy <= 1; ++dy){
        int yy = hh + dy; if ((unsigned)yy >= 16u) continue;
        #pragma unroll
        for (int dx = -1; dx <= 1; ++dx){
          int xx = ww + dx; if ((unsigned)xx >= 16u) continue;
          int p = yy * 16 + xx;
          u64 word = (p < 64) ? sw0 : (p < 128) ? sw1 : (p < 192) ? sw2 : sw3;
          if ((word >> (p & 63)) & 1ull) acc += cwv[(dy + 1) * 3 + (dx + 1)];
        }
      }
      float xv = xs[cl * 260 + n];
      xt[(((size_t)t * 16 + bb) * 256 + n) * 512 + c0 + cl] = xv + acc;
    }
    __syncthreads();
  }
}

// --- fused LayerNorm (over C) + LIF (over T) -> bit-packed spikes [m][8] u64 ---
// thread handles cols tid and tid+256 so each wave's ballot is one 64-col word
__global__ __launch_bounds__(256) void ln_lif_kernel(const float* __restrict__ xt,
    const float* __restrict__ g, const float* __restrict__ be,
    const float* __restrict__ lifw, int lidx, u64* __restrict__ obits){
  int bn = blockIdx.x; int tid = threadIdx.x;
  int lane = tid & 63, wid = tid >> 6;
  int c0 = tid, c1 = tid + 256;
  __shared__ float ps[8];
  float D = sigmoidf_(lifw[lidx]);
  float g0 = g[c0], g1 = g[c1];
  float b0 = be[c0], b1 = be[c1];
  float v0 = 0.f, v1 = 0.f;
  for (int t = 0; t < T_; ++t){
    size_t base = ((size_t)t * 4096 + bn) * 512;
    float x0 = xt[base + c0], x1 = xt[base + c1];
    float s = x0 + x1, q = x0 * x0 + x1 * x1;
    #pragma unroll
    for (int m = 32; m > 0; m >>= 1){
      s += __shfl_xor(s, m, 64);
      q += __shfl_xor(q, m, 64);
    }
    if (lane == 0){ ps[wid * 2] = s; ps[wid * 2 + 1] = q; }
    __syncthreads();
    float S = ps[0] + ps[2] + ps[4] + ps[6];
    float Q = ps[1] + ps[3] + ps[5] + ps[7];
    __syncthreads();
    float mean = S * (1.f / 512.f);
    float var = Q * (1.f / 512.f) - mean * mean;
    float inv = 1.f / sqrtf(var + 1e-5f);
    float y0 = (x0 - mean) * inv * g0 + b0;
    float y1 = (x1 - mean) * inv * g1 + b1;
    v0 = v0 + (y0 - v0) * D; bool s0 = v0 >= 1.f;
    v1 = v1 + (y1 - v1) * D; bool s1 = v1 >= 1.f;
    u64 bal0 = __ballot(s0);
    u64 bal1 = __ballot(s1);
    if (lane == 0){
      size_t rb = ((size_t)t * 4096 + bn) * 8;
      obits[rb + wid] = bal0;
      obits[rb + 4 + wid] = bal1;
    }
    v0 = s0 ? 0.f : v0; v1 = s1 ? 0.f : v1;
  }
}

// ------- LIF over [16384,512] f32 pre-acts -> bit-packed spikes [m][8] u64 -------
__global__ __launch_bounds__(256) void lif_bits_kernel(const float* __restrict__ in,
    u64* __restrict__ bits, const float* __restrict__ lifw, int lidx){
  int tid = blockIdx.x * 256 + threadIdx.x;
  int j = tid & 511; int bn = tid >> 9;
  float D = sigmoidf_(lifw[lidx]);
  float v = 0.f;
  #pragma unroll
  for (int t = 0; t < T_; ++t){
    int m = t * 4096 + bn;
    float xv = in[(size_t)m * 512 + j];
    v = v + (xv - v) * D;
    bool sp = v >= 1.f;
    u64 bal = __ballot(sp);
    if ((threadIdx.x & 63) == 0) bits[(size_t)m * 8 + (j >> 6)] = bal;
    v = sp ? 0.f : v;
  }
}

// ---- NT GEMM: A = bit-packed spikes (expanded in-register), split-bf16 weights ----
// M-tile rows r=0..127 map to g = (r>>5)*4096 + bn0 + (r&31)
// mode 0: xtio[g,col] += acc + bias
// mode 1: LIF(2+part) -> bit-packed to outBits (qkv: part=n0>>9, rs 8)
// mode 2: LIF(lidx) + bias -> bit-packed to outBits (fc1: rs 16)
// mode 3: acc + xtio -> final transposed store to outF [T,B,C,H,W]
__global__ __launch_bounds__(256) void gemm_fused(
    const u64* __restrict__ Abits, int ars,
    const unsigned short* __restrict__ Whi, const unsigned short* __restrict__ Wlo, int ldw,
    const float* __restrict__ bias,
    float* __restrict__ xtio, float* __restrict__ outF,
    u64* __restrict__ outBits,
    int K, int mode, const float* __restrict__ lifw, int lidx){
  extern __shared__ __align__(16) char smemraw[];
  unsigned short* Bh = (unsigned short*)smemraw;          // 8 KB
  unsigned short* Bl = (unsigned short*)(smemraw + 8192); // 8 KB
  u32* Alds = (u32*)(smemraw + 16384);                    // [K/32][128] u32
  int bn0 = blockIdx.x * 32;
  int n0  = blockIdx.y * 128;
  int tid = threadIdx.x, lane = tid & 63, wid = tid >> 6;
  int wm = (wid >> 1) * 64, wn = (wid & 1) * 64;
  int lm = lane & 15, quad = lane >> 4;
  int r4 = lane >> 2;
  int swz = ((lane & 3) ^ ((lane >> 3) & 3)) * 8;
  int rB0 = wid * 16 + r4, rB1 = rB0 + 64;
  const unsigned short* ph0 = Whi + (size_t)(n0 + rB0) * ldw + swz;
  const unsigned short* ph1 = Whi + (size_t)(n0 + rB1) * ldw + swz;
  const unsigned short* pl0 = Wlo + (size_t)(n0 + rB0) * ldw + swz;
  const unsigned short* pl1 = Wlo + (size_t)(n0 + rB1) * ldw + swz;
  int lofs = __builtin_amdgcn_readfirstlane(wid * 512);
  int sx = (quad ^ ((lm >> 1) & 3)) << 3;

  // stage A-bits word-major: Alds[w32][r]
  int nw64 = K >> 6;
  for (int i = tid; i < 128 * nw64; i += 256){
    int r = i & 127, w64 = i >> 7;
    size_t g = (size_t)((r >> 5) * 4096 + bn0 + (r & 31));
    u64 vbits = Abits[g * ars + w64];
    Alds[(2 * w64) * 128 + r]     = (u32)vbits;
    Alds[(2 * w64 + 1) * 128 + r] = (u32)(vbits >> 32);
  }

  floatx4 acc[4][4];
  #pragma unroll
  for (int i = 0; i < 4; ++i)
    #pragma unroll
    for (int j = 0; j < 4; ++j){ acc[i][j][0]=0.f; acc[i][j][1]=0.f; acc[i][j][2]=0.f; acc[i][j][3]=0.f; }

  for (int kb = 0; kb < K; kb += 32){
    gll16(ph0 + kb, Bh + lofs); gll16(ph1 + kb, Bh + 2048 + lofs);
    gll16(pl0 + kb, Bl + lofs); gll16(pl1 + kb, Bl + 2048 + lofs);
    __syncthreads();
    int wi = kb >> 5;
    short8 af[4], bh[4], bl[4];
    #pragma unroll
    for (int im = 0; im < 4; ++im){
      u32 wv = Alds[wi * 128 + wm + im * 16 + lm];
      u32 byte = (wv >> (quad * 8)) & 0xFFu;
      union { u32 u[4]; short8 s; } c;
      c.u[0] = ((byte & 1u)        | ((byte & 2u) << 15))        * 0x3F80u;
      c.u[1] = (((byte >> 2) & 1u) | (((byte >> 3) & 1u) << 16)) * 0x3F80u;
      c.u[2] = (((byte >> 4) & 1u) | (((byte >> 5) & 1u) << 16)) * 0x3F80u;
      c.u[3] = (((byte >> 6) & 1u) | (((byte >> 7) & 1u) << 16)) * 0x3F80u;
      af[im] = c.s;
    }
    #pragma unroll
    for (int in = 0; in < 4; ++in){
      bh[in] = *(const short8*)(&Bh[(wn + in * 16 + lm) * 32 + sx]);
      bl[in] = *(const short8*)(&Bl[(wn + in * 16 + lm) * 32 + sx]);
    }
    #pragma unroll
    for (int im = 0; im < 4; ++im)
      #pragma unroll
      for (int in = 0; in < 4; ++in){
        acc[im][in] = __builtin_amdgcn_mfma_f32_16x16x32_bf16(af[im], bh[in], acc[im][in], 0, 0, 0);
        acc[im][in] = __builtin_amdgcn_mfma_f32_16x16x32_bf16(af[im], bl[in], acc[im][in], 0, 0, 0);
      }
    __syncthreads();
  }

  if (mode == 0 || mode == 3){
    #pragma unroll
    for (int im = 0; im < 4; ++im){
      int tr0 = wm + im * 16 + quad * 4;
      #pragma unroll
      for (int in = 0; in < 4; ++in){
        int col = n0 + wn + in * 16 + lm;
        float bv = bias ? bias[col] : 0.f;
        #pragma unroll
        for (int r = 0; r < 4; ++r){
          int tr = tr0 + r;
          int t = tr >> 5; int bq = bn0 + (tr & 31);
          size_t gg = (size_t)t * 4096 + bq;
          float vv = acc[im][in][r] + bv + xtio[gg * 512 + col];
          if (mode == 0){
            xtio[gg * 512 + col] = vv;
          } else {
            int bb = bq >> 8, nn = bq & 255;
            outF[(((size_t)t * 16 + bb) * 512 + col) * 256 + nn] = vv;
          }
        }
      }
    }
    return;
  }

  // modes 1/2: LDS round-trip per 32-col chunk, LIF over t, bit-packed output
  float* cbuf = (float*)smemraw;                 // [128][36] f32
  u32* bits32 = (u32*)(smemraw + 20480);         // 512 u32
  u64* ob; int obrs, obwb;
  if (mode == 1){ ob = outBits + (size_t)(n0 >> 9) * 131072; obrs = 8; obwb = (n0 & 511) >> 6; }
  else          { ob = outBits; obrs = 16; obwb = n0 >> 6; }
  float D = sigmoidf_(lifw[mode == 1 ? (2 + (n0 >> 9)) : lidx]);
  bits32[tid] = 0; bits32[256 + tid] = 0;
  for (int ch = 0; ch < 4; ++ch){
    __syncthreads();
    if (wn == (ch >> 1) * 64){
      int in0 = (ch & 1) * 2;
      #pragma unroll
      for (int ii = 0; ii < 2; ++ii){
        int in = in0 + ii;
        int colL = in * 16 + lm - (ch & 1) * 32;
        #pragma unroll
        for (int im = 0; im < 4; ++im){
          int tr0 = wm + im * 16 + quad * 4;
          #pragma unroll
          for (int r = 0; r < 4; ++r) cbuf[(tr0 + r) * 36 + colL] = acc[im][in][r];
        }
      }
    }
    __syncthreads();
    int bnl = tid >> 3, c4 = (tid & 7) * 4;
    float b4[4];
    #pragma unroll
    for (int j = 0; j < 4; ++j) b4[j] = bias ? bias[n0 + ch * 32 + c4 + j] : 0.f;
    float vv[4] = {0.f, 0.f, 0.f, 0.f};
    #pragma unroll
    for (int t = 0; t < 4; ++t){
      int row = t * 32 + bnl;
      u32 nib = 0;
      #pragma unroll
      for (int j = 0; j < 4; ++j){
        float pre = cbuf[row * 36 + c4 + j] + b4[j];
        vv[j] = vv[j] + (pre - vv[j]) * D;
        bool s = vv[j] >= 1.f;
        nib |= (u32)s << j;
        vv[j] = s ? 0.f : vv[j];
      }
      if (nib) atomicOr(&bits32[row * 4 + ch], nib << c4);
    }
  }
  __syncthreads();
  {
    int t = tid >> 6, bnl = (tid >> 1) & 31, j = tid & 1;
    size_t g = (size_t)t * 4096 + bn0 + bnl;
    int idx = (t * 32 + bnl) * 4 + 2 * j;
    u64 wv = (u64)bits32[idx] | ((u64)bits32[idx + 1] << 32);
    ob[g * obrs + obwb + j] = wv;
  }
}

// ---- attention pre-acts per (t,b,h): a = (q @ kvm) * 0.125 via MFMA, kvm by popcount ----
__global__ __launch_bounds__(256) void attn_a_kernel(const u64* __restrict__ bits,
    float* __restrict__ aout){
  int tbh = blockIdx.x;
  int h = tbh & 7, b = (tbh >> 3) & 15, t = tbh >> 7;
  int m0 = t * 4096 + b * 256;
  int tid = threadIdx.x, lane = tid & 63, wid = tid >> 6;
  __shared__ u64 QW[256], KW[256], VW[256];
  __shared__ u64 kbt[64][4], vbt[64][4];
  __shared__ __align__(16) unsigned short Bs[64 * 72];
  {
    size_t base = (size_t)(m0 + tid) * 8 + h;
    QW[tid] = bits[base];
    KW[tid] = bits[131072 + base];
    VW[tid] = bits[262144 + base];
  }
  __syncthreads();
  {
    int i = tid & 63, w = tid >> 6;
    const u64* kwp = &KW[w * 64];
    const u64* vwp = &VW[w * 64];
    u64 bk = 0, bv = 0;
    for (int nn = 0; nn < 64; ++nn){
      bk |= ((kwp[nn] >> i) & 1ull) << nn;
      bv |= ((vwp[nn] >> i) & 1ull) << nn;
    }
    kbt[i][w] = bk; vbt[i][w] = bv;
  }
  __syncthreads();
  #pragma unroll
  for (int e = 0; e < 16; ++e){
    int idx = tid * 16 + e;
    int i = idx >> 6, j = idx & 63;
    int cnt = __popcll(kbt[i][0] & vbt[j][0]) + __popcll(kbt[i][1] & vbt[j][1])
            + __popcll(kbt[i][2] & vbt[j][2]) + __popcll(kbt[i][3] & vbt[j][3]);
    Bs[j * 72 + i] = f2b((float)cnt);
  }
  __syncthreads();
  int lm = lane & 15, quad = lane >> 4;
  int wm = wid * 64;
  u64 qw[4];
  #pragma unroll
  for (int im = 0; im < 4; ++im) qw[im] = QW[wm + im * 16 + lm];
  floatx4 acc[4][4];
  #pragma unroll
  for (int i = 0; i < 4; ++i)
    #pragma unroll
    for (int j = 0; j < 4; ++j){ acc[i][j][0]=0.f; acc[i][j][1]=0.f; acc[i][j][2]=0.f; acc[i][j][3]=0.f; }
  #pragma unroll
  for (int kb = 0; kb < 64; kb += 32){
    short8 af[4], bf[4];
    #pragma unroll
    for (int im = 0; im < 4; ++im){
      u32 byte = (u32)(qw[im] >> (kb + quad * 8)) & 0xFFu;
      union { u32 u[4]; short8 s; } c;
      c.u[0] = ((byte & 1u)        | ((byte & 2u) << 15))        * 0x3F80u;
      c.u[1] = (((byte >> 2) & 1u) | (((byte >> 3) & 1u) << 16)) * 0x3F80u;
      c.u[2] = (((byte >> 4) & 1u) | (((byte >> 5) & 1u) << 16)) * 0x3F80u;
      c.u[3] = (((byte >> 6) & 1u) | (((byte >> 7) & 1u) << 16)) * 0x3F80u;
      af[im] = c.s;
    }
    #pragma unroll
    for (int in = 0; in < 4; ++in)
      bf[in] = *(const short8*)(&Bs[(in * 16 + lm) * 72 + kb + quad * 8]);
    #pragma unroll
    for (int im = 0; im < 4; ++im)
      #pragma unroll
      for (int in = 0; in < 4; ++in)
        acc[im][in] = __builtin_amdgcn_mfma_f32_16x16x32_bf16(af[im], bf[in], acc[im][in], 0, 0, 0);
  }
  float* ob = aout + (size_t)m0 * 512 + h * 64;
  #pragma unroll
  for (int im = 0; im < 4; ++im){
    int nr0 = wm + im * 16 + quad * 4;
    #pragma unroll
    for (int in = 0; in < 4; ++in){
      int j = in * 16 + lm;
      #pragma unroll
      for (int r = 0; r < 4; ++r)
        ob[(size_t)(nr0 + r) * 512 + j] = acc[im][in][r] * 0.125f;
    }
  }
}

extern "C" void kernel_launch(void* const* d_in, const int* in_sizes, int n_in,
                              void* d_out, int out_size, void* d_ws, size_t ws_size,
                              hipStream_t stream){
  const float* x     = (const float*)d_in[0];
  const float* convw = (const float*)d_in[1];
  const float* convb = (const float*)d_in[2];
  const float* ln1g  = (const float*)d_in[3];
  const float* ln1b  = (const float*)d_in[4];
  const float* qkvw  = (const float*)d_in[5];
  const float* projw = (const float*)d_in[6];
  const float* projb = (const float*)d_in[7];
  const float* ln2g  = (const float*)d_in[8];
  const float* ln2b  = (const float*)d_in[9];
  const float* fc1w  = (const float*)d_in[10];
  const float* fc1b  = (const float*)d_in[11];
  const float* fc2w  = (const float*)d_in[12];
  const float* fc2b  = (const float*)d_in[13];
  const float* lifw  = (const float*)d_in[14];
  float* outp = (float*)d_out;

  // workspace layout (~87 MB)
  char* wsb = (char*)d_ws;
  float* XT           = (float*)wsb;                           // [16384,512] f32  33.5 MB
  float* AF32         = (float*)(wsb + 33554432);              // [16384,512] f32  33.5 MB
  unsigned short* WHI = (unsigned short*)(wsb + 67108864);     //  6.3 MB
  unsigned short* WLO = (unsigned short*)(wsb + 73400320);     //  6.3 MB
  u64* QBITS          = (u64*)(wsb + 79691776);                // [3,16384,8]  3.1 MB
  u64* H12            = (u64*)(wsb + 82837504);                // [16384,8]    1.0 MB
  u64* ASB            = (u64*)(wsb + 83886080);                // [16384,8]    1.0 MB
  u64* HBITS          = (u64*)(wsb + 84934656);                // [16384,16]   2.1 MB
  const int OFF_QKV = 0, OFF_PROJ = 786432, OFF_FC1 = 1048576, OFF_FC2 = 2097152;

  wsplit_kernel<<<12288, 256, 0, stream>>>(qkvw, projw, fc1w, fc2w, WHI, WLO);
  conv_lif_kernel<<<512, 256, 0, stream>>>(x, convw, convb, lifw, XT);
  // h1 bits
  ln_lif_kernel<<<4096, 256, 0, stream>>>(XT, ln1g, ln1b, lifw, 1, H12);
  // qkv GEMM + LIF -> bit-packed q,k,v
  gemm_fused<<<dim3(128, 12), 256, 24576, stream>>>(H12, 8,
      WHI + OFF_QKV, WLO + OFF_QKV, 512, nullptr,
      nullptr, nullptr, QBITS, 512, 1, lifw, 0);
  // attention pre-acts
  attn_a_kernel<<<512, 256, 0, stream>>>(QBITS, AF32);
  // a_s bits
  lif_bits_kernel<<<8192, 256, 0, stream>>>(AF32, ASB, lifw, 5);
  // xt += a_s @ proj^T + proj_b
  gemm_fused<<<dim3(128, 4), 256, 24576, stream>>>(ASB, 8,
      WHI + OFF_PROJ, WLO + OFF_PROJ, 512, projb,
      XT, nullptr, nullptr, 512, 0, lifw, 0);
  // h2 bits
  ln_lif_kernel<<<4096, 256, 0, stream>>>(XT, ln2g, ln2b, lifw, 6, H12);
  // MLP half 0
  gemm_fused<<<dim3(128, 8), 256, 24576, stream>>>(H12, 8,
      WHI + OFF_FC1, WLO + OFF_FC1, 512, fc1b,
      nullptr, nullptr, HBITS, 512, 2, lifw, 7);
  gemm_fused<<<dim3(128, 4), 256, 32768, stream>>>(HBITS, 16,
      WHI + OFF_FC2, WLO + OFF_FC2, 2048, fc2b,
      XT, nullptr, nullptr, 1024, 0, lifw, 0);
  // MLP half 1 (final fc2 writes output transposed)
  gemm_fused<<<dim3(128, 8), 256, 24576, stream>>>(H12, 8,
      WHI + OFF_FC1 + 524288, WLO + OFF_FC1 + 524288, 512, fc1b + 1024,
      nullptr, nullptr, HBITS, 512, 2, lifw, 7);
  gemm_fused<<<dim3(128, 4), 256, 32768, stream>>>(HBITS, 16,
      WHI + OFF_FC2 + 1024, WLO + OFF_FC2 + 1024, 2048, nullptr,
      XT, outp, nullptr, 1024, 3, lifw, 0);
}

// Round 8
// 453.370 us; speedup vs baseline: 2.1947x; 1.0754x over previous
//
#include <hip/hip_runtime.h>

typedef unsigned long long u64;
typedef unsigned int u32;
typedef float  floatx4 __attribute__((ext_vector_type(4)));
typedef short  short8  __attribute__((ext_vector_type(8)));

#define T_ 4

static __device__ __forceinline__ float b2f(unsigned short u){
  union { unsigned int i; float f; } x; x.i = ((unsigned int)u) << 16; return x.f;
}
static __device__ __forceinline__ unsigned short f2b(float f){
  unsigned int u = __float_as_uint(f);
  unsigned int r = (u + 0x7FFFu + ((u >> 16) & 1u)) >> 16;
  return (unsigned short)r;
}
static __device__ __forceinline__ float sigmoidf_(float x){ return 1.f / (1.f + expf(-x)); }

static __device__ __forceinline__ void gll16(const void* g, void* l){
  __builtin_amdgcn_global_load_lds(
      (const __attribute__((address_space(1))) void*)g,
      (__attribute__((address_space(3))) void*)l, 16, 0, 0);
}

// ------- split all weights into bf16 hi + bf16 lo (concatenated qkv|proj|fc1|fc2) -------
__global__ __launch_bounds__(256) void wsplit_kernel(const float* __restrict__ qkvw,
    const float* __restrict__ projw, const float* __restrict__ fc1w,
    const float* __restrict__ fc2w, unsigned short* __restrict__ hi,
    unsigned short* __restrict__ lo){
  int i = blockIdx.x * 256 + threadIdx.x;
  const float* src; int off;
  if (i < 786432)      { src = qkvw; off = i; }
  else if (i < 1048576){ src = projw; off = i - 786432; }
  else if (i < 2097152){ src = fc1w;  off = i - 1048576; }
  else                 { src = fc2w;  off = i - 2097152; }
  float f = src[off];
  unsigned short h = f2b(f);
  float r = f - b2f(h);
  hi[i] = h; lo[i] = f2b(r);
}

// ---- FUSED: lif(x) + depthwise 3x3 conv + residual + transpose to [T,B,N,C] f32 ----
__global__ __launch_bounds__(256) void conv_lif_kernel(const float* __restrict__ x,
    const float* __restrict__ cw, const float* __restrict__ cb,
    const float* __restrict__ lifw, float* __restrict__ xt){
  __shared__ __align__(16) float xs[16 * 260];
  __shared__ u64 sbits[16][5];
  int bb = blockIdx.x & 15, cg = blockIdx.x >> 4;
  int c0 = cg * 16;
  int tid = threadIdx.x;
  int lane = tid & 63, w = tid >> 6;
  int cl = tid & 15;
  float D = sigmoidf_(lifw[0]);
  float cwv[9];
  #pragma unroll
  for (int j = 0; j < 9; ++j) cwv[j] = cw[(c0 + cl) * 9 + j];
  float cbv = cb[c0 + cl];
  float v[16];
  #pragma unroll
  for (int k = 0; k < 16; ++k) v[k] = 0.f;

  for (int t = 0; t < T_; ++t){
    #pragma unroll
    for (int j = 0; j < 4; ++j){
      int kk = __builtin_amdgcn_readfirstlane(w + 4 * j);
      const float* grow = x + (((size_t)t * 16 + bb) * 512 + c0 + kk) * 256 + lane * 4;
      gll16(grow, &xs[kk * 260]);
    }
    __syncthreads();
    #pragma unroll
    for (int k = 0; k < 16; ++k){
      float xv = xs[k * 260 + tid];
      v[k] = v[k] + (xv - v[k]) * D;
      bool sp = v[k] >= 1.f;
      u64 bal = __ballot(sp);
      if (lane == 0) sbits[k][w] = bal;
      v[k] = sp ? 0.f : v[k];
    }
    __syncthreads();
    u64 sw0 = sbits[cl][0], sw1 = sbits[cl][1], sw2 = sbits[cl][2], sw3 = sbits[cl][3];
    #pragma unroll
    for (int i = 0; i < 16; ++i){
      int n = (tid >> 4) + 16 * i;
      int hh = n >> 4, ww = n & 15;
      float acc = cbv;
      #pragma unroll
      for (int dy = -1; dy <= 1; ++dy){
        int yy = hh + dy; if ((unsigned)yy >= 16u) continue;
        #pragma unroll
        for (int dx = -1; dx <= 1; ++dx){
          int xx = ww + dx; if ((unsigned)xx >= 16u) continue;
          int p = yy * 16 + xx;
          u64 word = (p < 64) ? sw0 : (p < 128) ? sw1 : (p < 192) ? sw2 : sw3;
          if ((word >> (p & 63)) & 1ull) acc += cwv[(dy + 1) * 3 + (dx + 1)];
        }
      }
      float xv = xs[cl * 260 + n];
      xt[(((size_t)t * 16 + bb) * 256 + n) * 512 + c0 + cl] = xv + acc;
    }
    __syncthreads();
  }
}

// --- fused LayerNorm (over C) + LIF (over T) -> bit-packed spikes [m][8] u64 ---
__global__ __launch_bounds__(256) void ln_lif_kernel(const float* __restrict__ xt,
    const float* __restrict__ g, const float* __restrict__ be,
    const float* __restrict__ lifw, int lidx, u64* __restrict__ obits){
  int bn = blockIdx.x; int tid = threadIdx.x;
  int lane = tid & 63, wid = tid >> 6;
  int c0 = tid, c1 = tid + 256;
  __shared__ float ps[8];
  float D = sigmoidf_(lifw[lidx]);
  float g0 = g[c0], g1 = g[c1];
  float b0 = be[c0], b1 = be[c1];
  float v0 = 0.f, v1 = 0.f;
  for (int t = 0; t < T_; ++t){
    size_t base = ((size_t)t * 4096 + bn) * 512;
    float x0 = xt[base + c0], x1 = xt[base + c1];
    float s = x0 + x1, q = x0 * x0 + x1 * x1;
    #pragma unroll
    for (int m = 32; m > 0; m >>= 1){
      s += __shfl_xor(s, m, 64);
      q += __shfl_xor(q, m, 64);
    }
    if (lane == 0){ ps[wid * 2] = s; ps[wid * 2 + 1] = q; }
    __syncthreads();
    float S = ps[0] + ps[2] + ps[4] + ps[6];
    float Q = ps[1] + ps[3] + ps[5] + ps[7];
    __syncthreads();
    float mean = S * (1.f / 512.f);
    float var = Q * (1.f / 512.f) - mean * mean;
    float inv = 1.f / sqrtf(var + 1e-5f);
    float y0 = (x0 - mean) * inv * g0 + b0;
    float y1 = (x1 - mean) * inv * g1 + b1;
    v0 = v0 + (y0 - v0) * D; bool s0 = v0 >= 1.f;
    v1 = v1 + (y1 - v1) * D; bool s1 = v1 >= 1.f;
    u64 bal0 = __ballot(s0);
    u64 bal1 = __ballot(s1);
    if (lane == 0){
      size_t rb = ((size_t)t * 4096 + bn) * 8;
      obits[rb + wid] = bal0;
      obits[rb + 4 + wid] = bal1;
    }
    v0 = s0 ? 0.f : v0; v1 = s1 ? 0.f : v1;
  }
}

// ------- LIF over [16384,512] f32 pre-acts -> bit-packed spikes [m][8] u64 -------
__global__ __launch_bounds__(256) void lif_bits_kernel(const float* __restrict__ in,
    u64* __restrict__ bits, const float* __restrict__ lifw, int lidx){
  int tid = blockIdx.x * 256 + threadIdx.x;
  int j = tid & 511; int bn = tid >> 9;
  float D = sigmoidf_(lifw[lidx]);
  float v = 0.f;
  #pragma unroll
  for (int t = 0; t < T_; ++t){
    int m = t * 4096 + bn;
    float xv = in[(size_t)m * 512 + j];
    v = v + (xv - v) * D;
    bool sp = v >= 1.f;
    u64 bal = __ballot(sp);
    if ((threadIdx.x & 63) == 0) bits[(size_t)m * 8 + (j >> 6)] = bal;
    v = sp ? 0.f : v;
  }
}

// ---- NT GEMM: A = bit-packed spikes (nibble-LUT expand), split-bf16 weights ----
// wave layout 1x4: each wave covers all 128 M-rows x 32 N-cols (acc[8][2])
// M rows r: g = (r>>5)*4096 + bn0 + (r&31)   (4 timesteps x 32 tokens)
// mode 0: xtio[g,col] += acc + bias
// mode 1: LIF(2+part) -> bit-packed to outBits (qkv; part = n0>>9, row-stride 8)
// mode 2: LIF(lidx) + bias -> bit-packed to outBits (fc1; row-stride 32)
// mode 3: acc + bias + xtio -> final transposed store to outF [T,B,C,H,W]
__global__ __launch_bounds__(256) void gemm_fused(
    const u64* __restrict__ Abits, int ars,
    const unsigned short* __restrict__ Whi, const unsigned short* __restrict__ Wlo, int ldw,
    const float* __restrict__ bias,
    float* __restrict__ xtio, float* __restrict__ outF,
    u64* __restrict__ outBits,
    int K, int mode, const float* __restrict__ lifw, int lidx){
  extern __shared__ __align__(16) char smemraw[];
  unsigned short* Bh = (unsigned short*)smemraw;           // 8 KB
  unsigned short* Bl = (unsigned short*)(smemraw + 8192);  // 8 KB
  u32* Alds = (u32*)(smemraw + 16384);                     // [K/32][128] u32
  u64* tab  = (u64*)(smemraw + 16384 + K * 16);            // 16 x u64 nibble LUT
  int bn0 = blockIdx.x * 32;
  int n0  = blockIdx.y * 128;
  int tid = threadIdx.x, lane = tid & 63, wid = tid >> 6;
  int wn = wid * 32;
  int lm = lane & 15, quad = lane >> 4;
  int qs = quad * 8;
  int r4 = lane >> 2;
  int swz = ((lane & 3) ^ ((lane >> 3) & 3)) * 8;
  int rB0 = wid * 16 + r4, rB1 = rB0 + 64;
  const unsigned short* ph0 = Whi + (size_t)(n0 + rB0) * ldw + swz;
  const unsigned short* ph1 = Whi + (size_t)(n0 + rB1) * ldw + swz;
  const unsigned short* pl0 = Wlo + (size_t)(n0 + rB0) * ldw + swz;
  const unsigned short* pl1 = Wlo + (size_t)(n0 + rB1) * ldw + swz;
  int lofs = __builtin_amdgcn_readfirstlane(wid * 512);
  int sx = (quad ^ ((lm >> 1) & 3)) << 3;

  // nibble -> 4 bf16 LUT (entry n on its own bank pair; reads broadcast/conflict-free)
  if (tid < 16){
    u64 e = 0;
    #pragma unroll
    for (int j = 0; j < 4; ++j) if ((tid >> j) & 1) e |= 0x3F80ull << (16 * j);
    tab[tid] = e;
  }
  // stage A-bits word-major: Alds[w32][row]
  int nw64 = K >> 6;
  for (int i = tid; i < 128 * nw64; i += 256){
    int r = i & 127, w64 = i >> 7;
    size_t g = (size_t)((r >> 5) * 4096 + bn0 + (r & 31));
    u64 vb = Abits[g * ars + w64];
    Alds[(2 * w64) * 128 + r]     = (u32)vb;
    Alds[(2 * w64 + 1) * 128 + r] = (u32)(vb >> 32);
  }

  floatx4 acc[8][2];
  #pragma unroll
  for (int i = 0; i < 8; ++i)
    #pragma unroll
    for (int j = 0; j < 2; ++j){ acc[i][j][0]=0.f; acc[i][j][1]=0.f; acc[i][j][2]=0.f; acc[i][j][3]=0.f; }

  for (int kb = 0; kb < K; kb += 32){
    gll16(ph0 + kb, Bh + lofs); gll16(ph1 + kb, Bh + 2048 + lofs);
    gll16(pl0 + kb, Bl + lofs); gll16(pl1 + kb, Bl + 2048 + lofs);
    __syncthreads();
    int wi = kb >> 5;
    short8 bh[2], bl[2];
    #pragma unroll
    for (int in = 0; in < 2; ++in){
      bh[in] = *(const short8*)(&Bh[(wn + in * 16 + lm) * 32 + sx]);
      bl[in] = *(const short8*)(&Bl[(wn + in * 16 + lm) * 32 + sx]);
    }
    #pragma unroll
    for (int im = 0; im < 8; ++im){
      u32 wv = Alds[wi * 128 + im * 16 + lm];
      u32 by = wv >> qs;
      union { u64 d[2]; short8 s; } c;
      c.d[0] = tab[by & 15u];
      c.d[1] = tab[(by >> 4) & 15u];
      acc[im][0] = __builtin_amdgcn_mfma_f32_16x16x32_bf16(c.s, bh[0], acc[im][0], 0, 0, 0);
      acc[im][1] = __builtin_amdgcn_mfma_f32_16x16x32_bf16(c.s, bh[1], acc[im][1], 0, 0, 0);
      acc[im][0] = __builtin_amdgcn_mfma_f32_16x16x32_bf16(c.s, bl[0], acc[im][0], 0, 0, 0);
      acc[im][1] = __builtin_amdgcn_mfma_f32_16x16x32_bf16(c.s, bl[1], acc[im][1], 0, 0, 0);
    }
    __syncthreads();
  }

  if (mode == 0 || mode == 3){
    #pragma unroll
    for (int im = 0; im < 8; ++im){
      int row0 = im * 16 + quad * 4;
      #pragma unroll
      for (int in = 0; in < 2; ++in){
        int col = n0 + wn + in * 16 + lm;
        float bv = bias ? bias[col] : 0.f;
        #pragma unroll
        for (int r = 0; r < 4; ++r){
          int row = row0 + r;
          int t = row >> 5; int bq = bn0 + (row & 31);
          size_t gg = (size_t)t * 4096 + bq;
          float vv = acc[im][in][r] + bv + xtio[gg * 512 + col];
          if (mode == 0){
            xtio[gg * 512 + col] = vv;
          } else {
            outF[(((size_t)t * 16 + (bq >> 8)) * 512 + col) * 256 + (bq & 255)] = vv;
          }
        }
      }
    }
    return;
  }

  // modes 1/2: pure-register LIF (all 4 timesteps of a token live in one lane),
  // ballot -> bit-packed output. token A = quad*4+r (im=2t), token B = 16+quad*4+r (im=2t+1)
  u32* bits32 = (u32*)(smemraw + 20480);         // [128][4] u32 (this block's 128 cols)
  u64* ob; int obrs, obwb;
  if (mode == 1){ ob = outBits + (size_t)(n0 >> 9) * 131072; obrs = 8; obwb = (n0 & 511) >> 6; }
  else          { ob = outBits; obrs = 32; obwb = n0 >> 6; }
  float D = sigmoidf_(lifw[mode == 1 ? (2 + (n0 >> 9)) : lidx]);
  float bv0 = bias ? bias[n0 + wn + lm] : 0.f;
  float bv1 = bias ? bias[n0 + wn + 16 + lm] : 0.f;
  #pragma unroll
  for (int r = 0; r < 4; ++r){
    float vA0 = 0.f, vA1 = 0.f, vB0 = 0.f, vB1 = 0.f;
    #pragma unroll
    for (int t = 0; t < 4; ++t){
      float pA0 = acc[2*t][0][r] + bv0;   vA0 += (pA0 - vA0) * D; bool sA0 = vA0 >= 1.f; vA0 = sA0 ? 0.f : vA0;
      float pA1 = acc[2*t][1][r] + bv1;   vA1 += (pA1 - vA1) * D; bool sA1 = vA1 >= 1.f; vA1 = sA1 ? 0.f : vA1;
      float pB0 = acc[2*t+1][0][r] + bv0; vB0 += (pB0 - vB0) * D; bool sB0 = vB0 >= 1.f; vB0 = sB0 ? 0.f : vB0;
      float pB1 = acc[2*t+1][1][r] + bv1; vB1 += (pB1 - vB1) * D; bool sB1 = vB1 >= 1.f; vB1 = sB1 ? 0.f : vB1;
      u64 balA0 = __ballot(sA0), balA1 = __ballot(sA1);
      u64 balB0 = __ballot(sB0), balB1 = __ballot(sB1);
      if (lane < 4){
        int q = lane;
        u32 wA = (u32)((balA0 >> (16*q)) & 0xFFFFull) | ((u32)((balA1 >> (16*q)) & 0xFFFFull) << 16);
        u32 wB = (u32)((balB0 >> (16*q)) & 0xFFFFull) | ((u32)((balB1 >> (16*q)) & 0xFFFFull) << 16);
        bits32[(t * 32 + q * 4 + r) * 4 + wid]      = wA;
        bits32[(t * 32 + 16 + q * 4 + r) * 4 + wid] = wB;
      }
    }
  }
  __syncthreads();
  {
    int t = tid >> 6, bnl = (tid >> 1) & 31, j = tid & 1;
    size_t g = (size_t)t * 4096 + bn0 + bnl;
    int idx = (t * 32 + bnl) * 4 + 2 * j;
    u64 wv = (u64)bits32[idx] | ((u64)bits32[idx + 1] << 32);
    ob[g * obrs + obwb + j] = wv;
  }
}

// ---- attention pre-acts per (t,b,h): a = (q @ kvm) * 0.125 via MFMA, kvm by popcount ----
__global__ __launch_bounds__(256) void attn_a_kernel(const u64* __restrict__ bits,
    float* __restrict__ aout){
  int tbh = blockIdx.x;
  int h = tbh & 7, b = (tbh >> 3) & 15, t = tbh >> 7;
  int m0 = t * 4096 + b * 256;
  int tid = threadIdx.x, lane = tid & 63, wid = tid >> 6;
  __shared__ u64 QW[256], KW[256], VW[256];
  __shared__ u64 kbt[64][4], vbt[64][4];
  __shared__ __align__(16) unsigned short Bs[64 * 72];
  {
    size_t base = (size_t)(m0 + tid) * 8 + h;
    QW[tid] = bits[base];
    KW[tid] = bits[131072 + base];
    VW[tid] = bits[262144 + base];
  }
  __syncthreads();
  {
    int i = tid & 63, w = tid >> 6;
    const u64* kwp = &KW[w * 64];
    const u64* vwp = &VW[w * 64];
    u64 bk = 0, bv = 0;
    for (int nn = 0; nn < 64; ++nn){
      bk |= ((kwp[nn] >> i) & 1ull) << nn;
      bv |= ((vwp[nn] >> i) & 1ull) << nn;
    }
    kbt[i][w] = bk; vbt[i][w] = bv;
  }
  __syncthreads();
  #pragma unroll
  for (int e = 0; e < 16; ++e){
    int idx = tid * 16 + e;
    int i = idx >> 6, j = idx & 63;
    int cnt = __popcll(kbt[i][0] & vbt[j][0]) + __popcll(kbt[i][1] & vbt[j][1])
            + __popcll(kbt[i][2] & vbt[j][2]) + __popcll(kbt[i][3] & vbt[j][3]);
    Bs[j * 72 + i] = f2b((float)cnt);
  }
  __syncthreads();
  int lm = lane & 15, quad = lane >> 4;
  int wm = wid * 64;
  u64 qw[4];
  #pragma unroll
  for (int im = 0; im < 4; ++im) qw[im] = QW[wm + im * 16 + lm];
  floatx4 acc[4][4];
  #pragma unroll
  for (int i = 0; i < 4; ++i)
    #pragma unroll
    for (int j = 0; j < 4; ++j){ acc[i][j][0]=0.f; acc[i][j][1]=0.f; acc[i][j][2]=0.f; acc[i][j][3]=0.f; }
  #pragma unroll
  for (int kb = 0; kb < 64; kb += 32){
    short8 af[4], bf[4];
    #pragma unroll
    for (int im = 0; im < 4; ++im){
      u32 byte = (u32)(qw[im] >> (kb + quad * 8)) & 0xFFu;
      union { u32 u[4]; short8 s; } c;
      c.u[0] = ((byte & 1u)        | ((byte & 2u) << 15))        * 0x3F80u;
      c.u[1] = (((byte >> 2) & 1u) | (((byte >> 3) & 1u) << 16)) * 0x3F80u;
      c.u[2] = (((byte >> 4) & 1u) | (((byte >> 5) & 1u) << 16)) * 0x3F80u;
      c.u[3] = (((byte >> 6) & 1u) | (((byte >> 7) & 1u) << 16)) * 0x3F80u;
      af[im] = c.s;
    }
    #pragma unroll
    for (int in = 0; in < 4; ++in)
      bf[in] = *(const short8*)(&Bs[(in * 16 + lm) * 72 + kb + quad * 8]);
    #pragma unroll
    for (int im = 0; im < 4; ++im)
      #pragma unroll
      for (int in = 0; in < 4; ++in)
        acc[im][in] = __builtin_amdgcn_mfma_f32_16x16x32_bf16(af[im], bf[in], acc[im][in], 0, 0, 0);
  }
  float* ob = aout + (size_t)m0 * 512 + h * 64;
  #pragma unroll
  for (int im = 0; im < 4; ++im){
    int nr0 = wm + im * 16 + quad * 4;
    #pragma unroll
    for (int in = 0; in < 4; ++in){
      int j = in * 16 + lm;
      #pragma unroll
      for (int r = 0; r < 4; ++r)
        ob[(size_t)(nr0 + r) * 512 + j] = acc[im][in][r] * 0.125f;
    }
  }
}

extern "C" void kernel_launch(void* const* d_in, const int* in_sizes, int n_in,
                              void* d_out, int out_size, void* d_ws, size_t ws_size,
                              hipStream_t stream){
  const float* x     = (const float*)d_in[0];
  const float* convw = (const float*)d_in[1];
  const float* convb = (const float*)d_in[2];
  const float* ln1g  = (const float*)d_in[3];
  const float* ln1b  = (const float*)d_in[4];
  const float* qkvw  = (const float*)d_in[5];
  const float* projw = (const float*)d_in[6];
  const float* projb = (const float*)d_in[7];
  const float* ln2g  = (const float*)d_in[8];
  const float* ln2b  = (const float*)d_in[9];
  const float* fc1w  = (const float*)d_in[10];
  const float* fc1b  = (const float*)d_in[11];
  const float* fc2w  = (const float*)d_in[12];
  const float* fc2b  = (const float*)d_in[13];
  const float* lifw  = (const float*)d_in[14];
  float* outp = (float*)d_out;

  // workspace layout (~89 MB)
  char* wsb = (char*)d_ws;
  float* XT           = (float*)wsb;                           // [16384,512] f32  33.5 MB
  float* AF32         = (float*)(wsb + 33554432);              // [16384,512] f32  33.5 MB
  unsigned short* WHI = (unsigned short*)(wsb + 67108864);     //  6.3 MB
  unsigned short* WLO = (unsigned short*)(wsb + 73400320);     //  6.3 MB
  u64* QBITS          = (u64*)(wsb + 79691776);                // [3,16384,8]  3.1 MB
  u64* H12            = (u64*)(wsb + 82837504);                // [16384,8]    1.0 MB
  u64* ASB            = (u64*)(wsb + 83886080);                // [16384,8]    1.0 MB
  u64* HBITS          = (u64*)(wsb + 84934656);                // [16384,32]   4.2 MB
  const int OFF_QKV = 0, OFF_PROJ = 786432, OFF_FC1 = 1048576, OFF_FC2 = 2097152;

  wsplit_kernel<<<12288, 256, 0, stream>>>(qkvw, projw, fc1w, fc2w, WHI, WLO);
  conv_lif_kernel<<<512, 256, 0, stream>>>(x, convw, convb, lifw, XT);
  // h1 bits
  ln_lif_kernel<<<4096, 256, 0, stream>>>(XT, ln1g, ln1b, lifw, 1, H12);
  // qkv GEMM + LIF -> bit-packed q,k,v       (dyn LDS: 16384 + K*16 + 128)
  gemm_fused<<<dim3(128, 12), 256, 24704, stream>>>(H12, 8,
      WHI + OFF_QKV, WLO + OFF_QKV, 512, nullptr,
      nullptr, nullptr, QBITS, 512, 1, lifw, 0);
  // attention pre-acts
  attn_a_kernel<<<512, 256, 0, stream>>>(QBITS, AF32);
  // a_s bits
  lif_bits_kernel<<<8192, 256, 0, stream>>>(AF32, ASB, lifw, 5);
  // xt += a_s @ proj^T + proj_b
  gemm_fused<<<dim3(128, 4), 256, 24704, stream>>>(ASB, 8,
      WHI + OFF_PROJ, WLO + OFF_PROJ, 512, projb,
      XT, nullptr, nullptr, 512, 0, lifw, 0);
  // h2 bits
  ln_lif_kernel<<<4096, 256, 0, stream>>>(XT, ln2g, ln2b, lifw, 6, H12);
  // fc1 (merged, N=2048) + LIF -> HBITS
  gemm_fused<<<dim3(128, 16), 256, 24704, stream>>>(H12, 8,
      WHI + OFF_FC1, WLO + OFF_FC1, 512, fc1b,
      nullptr, nullptr, HBITS, 512, 2, lifw, 7);
  // fc2 (merged, K=2048) + residual -> final transposed output
  gemm_fused<<<dim3(128, 4), 256, 49280, stream>>>(HBITS, 32,
      WHI + OFF_FC2, WLO + OFF_FC2, 2048, fc2b,
      XT, outp, nullptr, 2048, 3, lifw, 0);
}